// Round 5
// baseline (419.113 us; speedup 1.0000x reference)
//
#include <hip/hip_runtime.h>
#include <math.h>

#define TSEQ  2048
#define BATCH 2
#define NH    16
#define HD    64
#define CDIM  1024
#define N3C   3072
#define EPSY  1e-6f

typedef unsigned short u16;
typedef unsigned int u32;
typedef __attribute__((ext_vector_type(8))) short bf16x8;
typedef __attribute__((ext_vector_type(4))) float f32x4;

#define MFMA16(a, b, c) __builtin_amdgcn_mfma_f32_16x16x32_bf16(a, b, c, 0, 0, 0)

__device__ __forceinline__ u16 f2bf(float f) {
    unsigned u = __float_as_uint(f);
    return (u16)((u + 0x7fffu + ((u >> 16) & 1u)) >> 16);
}
__device__ __forceinline__ float bf2f(u16 h) {
    return __uint_as_float(((unsigned)h) << 16);
}
__device__ __forceinline__ void gload16(const void* g, void* l) {
    __builtin_amdgcn_global_load_lds(
        (const __attribute__((address_space(1))) unsigned int*)g,
        (__attribute__((address_space(3))) unsigned int*)l, 16, 0, 0);
}

// ---------------------------------------------------------------------------
__global__ void colsq_kernel(const float* __restrict__ wa,
                             const float* __restrict__ wp,
                             float* __restrict__ ks) {
    int bid = blockIdx.x, tid = threadIdx.x;
    int c = tid & 63, kq = tid >> 6;
    const float* W; int N, col, outoff;
    if (bid < 48) { W = wa; N = N3C;  col = bid * 64 + c;        outoff = 0;   }
    else          { W = wp; N = CDIM; col = (bid - 48) * 64 + c; outoff = N3C; }
    float s = 0.f;
    int i0 = kq * 256;
    #pragma unroll 4
    for (int i = i0; i < i0 + 256; ++i) {
        float v = W[(size_t)i * N + col];
        s = fmaf(v, v, s);
    }
    __shared__ float red[256];
    red[tid] = s;
    __syncthreads();
    if (kq == 0) ks[outoff + col] = red[c] + red[64 + c] + red[128 + c] + red[192 + c];
}

// ---------------------------------------------------------------------------
__global__ void convert_rows(const float* __restrict__ X, u16* __restrict__ Xhi,
                             u16* __restrict__ Xlo, float* __restrict__ rsq) {
    int row = blockIdx.x, tid = threadIdx.x;
    int lane = tid & 63, wv = tid >> 6;
    size_t base = (size_t)row * CDIM + tid * 4;
    float4 v = *(const float4*)(X + base);
    ushort4 hi, lo;
    hi.x = f2bf(v.x); lo.x = f2bf(v.x - bf2f(hi.x));
    hi.y = f2bf(v.y); lo.y = f2bf(v.y - bf2f(hi.y));
    hi.z = f2bf(v.z); lo.z = f2bf(v.z - bf2f(hi.z));
    hi.w = f2bf(v.w); lo.w = f2bf(v.w - bf2f(hi.w));
    *(ushort4*)(Xhi + base) = hi;
    *(ushort4*)(Xlo + base) = lo;
    float s = v.x * v.x + v.y * v.y + v.z * v.z + v.w * v.w;
    #pragma unroll
    for (int off = 32; off; off >>= 1) s += __shfl_down(s, off, 64);
    __shared__ float red[4];
    if (lane == 0) red[wv] = s;
    __syncthreads();
    if (tid == 0) rsq[row] = red[0] + red[1] + red[2] + red[3];
}

// ---------------------------------------------------------------------------
__global__ void convert_wT(const float* __restrict__ W, u16* __restrict__ Whi,
                           u16* __restrict__ Wlo, int K, int N) {
    __shared__ float tile[64][68];
    int k0 = blockIdx.y * 64, n0 = blockIdx.x * 64;
    int tid = threadIdx.x;
    int r = tid >> 4, c4 = (tid & 15) * 4;
    #pragma unroll
    for (int i = 0; i < 4; ++i) {
        int k = k0 + r + i * 16;
        float4 v = *(const float4*)(W + (size_t)k * N + n0 + c4);
        *(float4*)&tile[r + i * 16][c4] = v;
    }
    __syncthreads();
    int n = tid >> 4, k4 = (tid & 15) * 4;
    #pragma unroll
    for (int i = 0; i < 4; ++i) {
        int nn = n + i * 16;
        float a = tile[k4 + 0][nn], b = tile[k4 + 1][nn];
        float c = tile[k4 + 2][nn], d = tile[k4 + 3][nn];
        ushort4 hi, lo;
        hi.x = f2bf(a); lo.x = f2bf(a - bf2f(hi.x));
        hi.y = f2bf(b); lo.y = f2bf(b - bf2f(hi.y));
        hi.z = f2bf(c); lo.z = f2bf(c - bf2f(hi.z));
        hi.w = f2bf(d); lo.w = f2bf(d - bf2f(hi.w));
        size_t o = (size_t)(n0 + nn) * K + k0 + k4;
        *(ushort4*)(Whi + o) = hi;
        *(ushort4*)(Wlo + o) = lo;
    }
}

// ---------------------------------------------------------------------------
// GEMM1: split-bf16 MFMA, yat epilogue fused with rotary + bf16 pack.
// LDS staging XOR-swizzled: row r's k-chunk c stored at pos (c+(r>>1))&3;
// fragment read pos (quad+(l15>>1))&3 — 2-way max bank aliasing (free).
__global__ __launch_bounds__(256) void gemm1_fused(
    const u16* __restrict__ Ah, const u16* __restrict__ Al,
    const u16* __restrict__ Bh, const u16* __restrict__ Bl,
    const float* __restrict__ bias, const float* __restrict__ rowsq,
    const float* __restrict__ colsq, const float* __restrict__ alphap,
    u16* __restrict__ Qb, u16* __restrict__ Kb, u16* __restrict__ Vt) {
    constexpr int BK = 32;
    const int K = CDIM;
    __shared__ u16 Ash[128 * BK], Asl[128 * BK], Bsh[128 * BK], Bsl[128 * BK];
    int tid = threadIdx.x;
    int lane = tid & 63, wv = tid >> 6;
    int quad = lane >> 4, l15 = lane & 15;
    int wr = wv >> 1, wc = wv & 1;
    int bm = blockIdx.y * 128, bn = blockIdx.x * 128;
    int rsub = lane >> 2;
    int lc8 = (lane & 3) * 8;                          // LDS chunk offset
    int gc8 = (((lane & 3) - (rsub >> 1)) & 3) * 8;    // swizzled global chunk
    int pf8 = ((quad + (l15 >> 1)) & 3) * 8;           // fragment read pos

    f32x4 acc[4][4];
    #pragma unroll
    for (int i = 0; i < 4; ++i)
        #pragma unroll
        for (int j = 0; j < 4; ++j) acc[i][j] = (f32x4){0.f, 0.f, 0.f, 0.f};

    for (int kt = 0; kt < K; kt += BK) {
        #pragma unroll
        for (int i = 0; i < 2; ++i) {
            int r = i * 64 + wv * 16 + rsub;
            size_t go = (size_t)(bm + r) * K + kt + gc8;
            gload16(Ah + go, &Ash[r * BK + lc8]);
            gload16(Al + go, &Asl[r * BK + lc8]);
            size_t gb = (size_t)(bn + r) * K + kt + gc8;
            gload16(Bh + gb, &Bsh[r * BK + lc8]);
            gload16(Bl + gb, &Bsl[r * BK + lc8]);
        }
        __syncthreads();
        bf16x8 fah[4], fal[4], fbh[4], fbl[4];
        #pragma unroll
        for (int i = 0; i < 4; ++i) {
            int r = wr * 64 + i * 16 + l15;
            fah[i] = *(const bf16x8*)&Ash[r * BK + pf8];
            fal[i] = *(const bf16x8*)&Asl[r * BK + pf8];
        }
        #pragma unroll
        for (int j = 0; j < 4; ++j) {
            int r = wc * 64 + j * 16 + l15;
            fbh[j] = *(const bf16x8*)&Bsh[r * BK + pf8];
            fbl[j] = *(const bf16x8*)&Bsl[r * BK + pf8];
        }
        #pragma unroll
        for (int i = 0; i < 4; ++i)
            #pragma unroll
            for (int j = 0; j < 4; ++j) {
                acc[i][j] = MFMA16(fah[i], fbh[j], acc[i][j]);
                acc[i][j] = MFMA16(fal[i], fbh[j], acc[i][j]);
                acc[i][j] = MFMA16(fah[i], fbl[j], acc[i][j]);
            }
        __syncthreads();
    }

    float alpha = alphap[0];
    float scale = powf(sqrtf((float)N3C) / logf(1.0f + (float)N3C), alpha);
    int segc0 = bn + wc * 64;          // wave-uniform
    int seg = segc0 >> 10;             // 0=Q 1=K 2=V
    int h = (segc0 >> 6) & 15;
    int bglob = bm >> 11;
    int bh = bglob * NH + h;

    if (seg < 2) {
        u16* dst = (seg == 0) ? Qb : Kb;
        float qs = (seg == 0) ? 0.125f : 1.0f;
        float inv0 = exp2f(-(float)l15 * 0.4152410118609203f);
        float inv1 = exp2f(-(float)(l15 + 16) * 0.4152410118609203f);
        #pragma unroll
        for (int i = 0; i < 4; ++i) {
            int tb = bm + wr * 64 + i * 16 + quad * 4;
            #pragma unroll
            for (int r = 0; r < 4; ++r) {
                int row = tb + r;
                int t = row & (TSEQ - 1);
                float rs = rowsq[row];
                float y[4];
                #pragma unroll
                for (int j = 0; j < 4; ++j) {
                    int col = segc0 + j * 16 + l15;
                    float dot = acc[i][j][r];
                    float dist = rs + colsq[col] - 2.0f * dot + EPSY;
                    y[j] = dot * dot / dist * scale + bias[col];
                }
                float s0, c0, s1, c1;
                sincosf((float)t * inv0, &s0, &c0);
                sincosf((float)t * inv1, &s1, &c1);
                size_t ob = ((size_t)bh * TSEQ + t) * HD;
                dst[ob + l15]      = f2bf((y[0] * c0 - y[2] * s0) * qs);
                dst[ob + 16 + l15] = f2bf((y[1] * c1 - y[3] * s1) * qs);
                dst[ob + 32 + l15] = f2bf((y[2] * c0 + y[0] * s0) * qs);
                dst[ob + 48 + l15] = f2bf((y[3] * c1 + y[1] * s1) * qs);
            }
        }
    } else {
        #pragma unroll
        for (int i = 0; i < 4; ++i) {
            int tb = bm + wr * 64 + i * 16 + quad * 4;
            int t0 = tb & (TSEQ - 1);
            #pragma unroll
            for (int j = 0; j < 4; ++j) {
                int col = segc0 + j * 16 + l15;
                int d = j * 16 + l15;
                float cs = colsq[col], bi = bias[col];
                ushort4 pk;
                u16* pp = (u16*)&pk;
                #pragma unroll
                for (int r = 0; r < 4; ++r) {
                    float dot = acc[i][j][r];
                    float dist = rowsq[tb + r] + cs - 2.0f * dot + EPSY;
                    pp[r] = f2bf(dot * dot / dist * scale + bi);
                }
                *(ushort4*)(Vt + ((size_t)bh * HD + d) * TSEQ + t0) = pk;
            }
        }
    }
}

// ---------------------------------------------------------------------------
// GEMM2: split-bf16 MFMA + yat epilogue, fp32 out. (128x64 tile, swizzled LDS)
__global__ __launch_bounds__(256) void gemm_yat_mfma(
    const u16* __restrict__ Ah, const u16* __restrict__ Al,
    const u16* __restrict__ Bh, const u16* __restrict__ Bl,
    const float* __restrict__ bias, const float* __restrict__ rowsq,
    const float* __restrict__ colsq, const float* __restrict__ alphap,
    float* __restrict__ outp, int M, int N, int K, float outf) {
    constexpr int BM = 128, BN = 64, BK = 32;
    __shared__ u16 Ash[BM * BK], Asl[BM * BK], Bsh[BN * BK], Bsl[BN * BK];
    int tid = threadIdx.x;
    int lane = tid & 63, wv = tid >> 6;
    int quad = lane >> 4, l15 = lane & 15;
    int bm = blockIdx.y * BM, bn = blockIdx.x * BN;
    int rsub = lane >> 2;
    int lc8 = (lane & 3) * 8;
    int gc8 = (((lane & 3) - (rsub >> 1)) & 3) * 8;
    int pf8 = ((quad + (l15 >> 1)) & 3) * 8;

    f32x4 acc[2][4];
    #pragma unroll
    for (int i = 0; i < 2; ++i)
        #pragma unroll
        for (int j = 0; j < 4; ++j) acc[i][j] = (f32x4){0.f, 0.f, 0.f, 0.f};

    for (int kt = 0; kt < K; kt += BK) {
        #pragma unroll
        for (int i = 0; i < 2; ++i) {
            int r = i * 64 + wv * 16 + rsub;
            size_t go = (size_t)(bm + r) * K + kt + gc8;
            gload16(Ah + go, &Ash[r * BK + lc8]);
            gload16(Al + go, &Asl[r * BK + lc8]);
        }
        {
            int r = wv * 16 + rsub;
            size_t go = (size_t)(bn + r) * K + kt + gc8;
            gload16(Bh + go, &Bsh[r * BK + lc8]);
            gload16(Bl + go, &Bsl[r * BK + lc8]);
        }
        __syncthreads();
        bf16x8 fah[2], fal[2], fbh[4], fbl[4];
        #pragma unroll
        for (int i = 0; i < 2; ++i) {
            int r = wv * 32 + i * 16 + l15;
            fah[i] = *(const bf16x8*)&Ash[r * BK + pf8];
            fal[i] = *(const bf16x8*)&Asl[r * BK + pf8];
        }
        #pragma unroll
        for (int j = 0; j < 4; ++j) {
            int r = j * 16 + l15;
            fbh[j] = *(const bf16x8*)&Bsh[r * BK + pf8];
            fbl[j] = *(const bf16x8*)&Bsl[r * BK + pf8];
        }
        #pragma unroll
        for (int i = 0; i < 2; ++i)
            #pragma unroll
            for (int j = 0; j < 4; ++j) {
                acc[i][j] = MFMA16(fah[i], fbh[j], acc[i][j]);
                acc[i][j] = MFMA16(fal[i], fbh[j], acc[i][j]);
                acc[i][j] = MFMA16(fah[i], fbl[j], acc[i][j]);
            }
        __syncthreads();
    }

    float alpha = alphap[0];
    float scale = powf(sqrtf(outf) / logf(1.0f + outf), alpha);
    #pragma unroll
    for (int j = 0; j < 4; ++j) {
        int col = bn + j * 16 + l15;
        float cs = colsq[col], bi = bias[col];
        #pragma unroll
        for (int i = 0; i < 2; ++i) {
            #pragma unroll
            for (int r = 0; r < 4; ++r) {
                int row = bm + wv * 32 + i * 16 + quad * 4 + r;
                float dot = acc[i][j][r];
                float dist = rowsq[row] + cs - 2.0f * dot + EPSY;
                outp[(size_t)row * N + col] = dot * dot / dist * scale + bi;
            }
        }
    }
}

// ---------------------------------------------------------------------------
// S^T-formulation bf16 MFMA causal flash attention.
// One 64-query block (qb) per block, 128-key tiles. grid (32, B*H),
// descending qb for load balance. Fully-masked upper half-tiles (~3% extra
// MFMA) are masked in the last iteration only.
__global__ __launch_bounds__(256) void attn_mfma(
    const u16* __restrict__ Qb, const u16* __restrict__ Kb,
    const u16* __restrict__ Vt, float* __restrict__ ctx) {
    __shared__ u16 Ksh[128 * 64];   // [key][d-chunks, rotated by key]
    __shared__ u16 Vsh[64 * 128];   // [d][key-chunks(16), rotated by d]
    int tid = threadIdx.x;
    int lane = tid & 63, wv = tid >> 6;
    int quad = lane >> 4, l15 = lane & 15;
    int bh = blockIdx.y;
    int b = bh >> 4, h = bh & 15;
    const u16* Qh = Qb + (size_t)bh * TSEQ * HD;
    const u16* Kh = Kb + (size_t)bh * TSEQ * HD;
    const u16* Vh = Vt + (size_t)bh * HD * TSEQ;
    const f32x4 zf = {0.f, 0.f, 0.f, 0.f};

    int qb = 31 - blockIdx.x;
    int qw = qb * 64 + wv * 16;
    bf16x8 bq0 = *(const bf16x8*)(Qh + (size_t)(qw + l15) * HD + quad * 8);
    bf16x8 bq1 = *(const bf16x8*)(Qh + (size_t)(qw + l15) * HD + 32 + quad * 8);

    f32x4 o[4] = {zf, zf, zf, zf};
    float m = -1e30f, l = 0.f;

    int nkt = (qb + 2) >> 1;
    for (int kt = 0; kt < nkt; ++kt) {
        int k0 = kt * 128;
        __syncthreads();
        #pragma unroll
        for (int p = 0; p < 4; ++p) {
            int lin = p * 256 + tid;
            int row = lin >> 3, ch = lin & 7;
            int gk = (ch + row) & 7;
            gload16(Kh + (size_t)(k0 + row) * HD + gk * 8, &Ksh[lin * 8]);
            int d = lin >> 4, cv = lin & 15;
            int gv = (cv + d) & 15;
            gload16(Vh + (size_t)d * TSEQ + k0 + gv * 8, &Vsh[lin * 8]);
        }
        __syncthreads();

        // S^T: 8 key-tiles x 2 d-steps
        f32x4 st[8];
        #pragma unroll
        for (int mt = 0; mt < 8; ++mt) {
            int key = mt * 16 + l15;
            bf16x8 a0 = *(const bf16x8*)&Ksh[key * 64 + ((quad - key) & 7) * 8];
            bf16x8 a1 = *(const bf16x8*)&Ksh[key * 64 + ((4 + quad - key) & 7) * 8];
            st[mt] = MFMA16(a0, bq0, zf);
            st[mt] = MFMA16(a1, bq1, st[mt]);
        }
        if (kt == nkt - 1) {   // causal mask (boundary lies in the last iter)
            int q = qw + l15;
            #pragma unroll
            for (int mt = 0; mt < 8; ++mt)
                #pragma unroll
                for (int r = 0; r < 4; ++r)
                    if (k0 + mt * 16 + quad * 4 + r > q) st[mt][r] = -1e30f;
        }
        // softmax over keys (regs + cross-quad reduce; lane l15 = query)
        float mx = -1e30f;
        #pragma unroll
        for (int mt = 0; mt < 8; ++mt)
            #pragma unroll
            for (int r = 0; r < 4; ++r) mx = fmaxf(mx, st[mt][r]);
        mx = fmaxf(mx, __shfl_xor(mx, 16, 64));
        mx = fmaxf(mx, __shfl_xor(mx, 32, 64));
        float mn = fmaxf(m, mx);
        float al = __expf(m - mn);
        m = mn;
        float ps = 0.f;
        u32 pp[8][2];
        #pragma unroll
        for (int mt = 0; mt < 8; ++mt) {
            float p0 = __expf(st[mt][0] - mn);
            float p1 = __expf(st[mt][1] - mn);
            float p2 = __expf(st[mt][2] - mn);
            float p3 = __expf(st[mt][3] - mn);
            ps += (p0 + p1) + (p2 + p3);
            pp[mt][0] = (u32)f2bf(p0) | ((u32)f2bf(p1) << 16);
            pp[mt][1] = (u32)f2bf(p2) | ((u32)f2bf(p3) << 16);
        }
        ps += __shfl_xor(ps, 16, 64);
        ps += __shfl_xor(ps, 32, 64);
        l = l * al + ps;
        #pragma unroll
        for (int dt = 0; dt < 4; ++dt) {
            o[dt][0] *= al; o[dt][1] *= al; o[dt][2] *= al; o[dt][3] *= al;
        }
        // PV: 4 k-steps of 32 keys. Shuffle BOTH mt-candidates, select on
        // the DESTINATION side (source-side quad differs — R3 lesson).
        #pragma unroll
        for (int s = 0; s < 4; ++s) {
            u32 bw[4];
            #pragma unroll
            for (int w = 0; w < 4; ++w) {
                int srcl = (((quad & 1) * 2 + (w >> 1)) << 4) + l15;
                u32 vlo = (u32)__shfl((int)pp[2 * s][w & 1], srcl, 64);
                u32 vhi = (u32)__shfl((int)pp[2 * s + 1][w & 1], srcl, 64);
                bw[w] = (quad & 2) ? vhi : vlo;
            }
            bf16x8 bfr;
            *(u32*)&((short*)&bfr)[0] = bw[0];
            *(u32*)&((short*)&bfr)[2] = bw[1];
            *(u32*)&((short*)&bfr)[4] = bw[2];
            *(u32*)&((short*)&bfr)[6] = bw[3];
            #pragma unroll
            for (int dt = 0; dt < 4; ++dt) {
                int d = dt * 16 + l15;
                bf16x8 av = *(const bf16x8*)&Vsh[d * 128 + ((s * 4 + quad - d) & 15) * 8];
                o[dt] = MFMA16(av, bfr, o[dt]);
            }
        }
    }

    float inv = 1.0f / l;
    #pragma unroll
    for (int dt = 0; dt < 4; ++dt) {
        float4 r;
        r.x = o[dt][0] * inv; r.y = o[dt][1] * inv;
        r.z = o[dt][2] * inv; r.w = o[dt][3] * inv;
        *(float4*)(ctx + ((size_t)b * TSEQ + qw + l15) * CDIM
                   + h * HD + dt * 16 + quad * 4) = r;
    }
}

// ---------------------------------------------------------------------------
extern "C" void kernel_launch(void* const* d_in, const int* in_sizes, int n_in,
                              void* d_out, int out_size, void* d_ws, size_t ws_size,
                              hipStream_t stream) {
    const float* x      = (const float*)d_in[0];
    const float* w_attn = (const float*)d_in[2];
    const float* b_attn = (const float*)d_in[3];
    const float* a_attn = (const float*)d_in[4];
    const float* w_proj = (const float*)d_in[5];
    const float* b_proj = (const float*)d_in[6];
    const float* a_proj = (const float*)d_in[7];
    float* outp = (float*)d_out;

    char* ws = (char*)d_ws;
    float* ksq = (float*)(ws);
    float* xsq = (float*)(ws + 16384);
    float* osq = (float*)(ws + 32768);
    char* pA  = ws + 65536;                    // 16.78 MB: Ahi/Alo -> ctx
    u16* Ahi = (u16*)pA;
    u16* Alo = (u16*)(pA + 8388608);
    float* ctx = (float*)pA;                   // alias (A dead after GEMM1)
    char* pWt = pA + 16777216;                 // 12.58 MB
    u16* Wthi = (u16*)pWt;
    u16* Wtlo = (u16*)(pWt + 6291456);
    char* pWp = pWt + 12582912;                // 4.19 MB
    u16* Wphi = (u16*)pWp;
    u16* Wplo = (u16*)(pWp + 2097152);
    char* pQ = pWp + 4194304;                  // 25.17 MB: Qb,Kb,Vt
    u16* Qb = (u16*)pQ;
    u16* Kb = (u16*)(pQ + 8388608);
    u16* Vt = (u16*)(pQ + 16777216);
    u16* Chi = (u16*)pQ;                       // alias (Q/K dead after attn)
    u16* Clo = (u16*)(pQ + 8388608);

    colsq_kernel<<<64, 256, 0, stream>>>(w_attn, w_proj, ksq);
    convert_rows<<<BATCH * TSEQ, 256, 0, stream>>>(x, Ahi, Alo, xsq);
    convert_wT<<<dim3(N3C / 64, CDIM / 64), 256, 0, stream>>>(w_attn, Wthi, Wtlo, CDIM, N3C);
    convert_wT<<<dim3(CDIM / 64, CDIM / 64), 256, 0, stream>>>(w_proj, Wphi, Wplo, CDIM, CDIM);
    gemm1_fused<<<dim3(N3C / 128, (BATCH * TSEQ) / 128), 256, 0, stream>>>(
        Ahi, Alo, Wthi, Wtlo, b_attn, xsq, ksq, a_attn, Qb, Kb, Vt);
    attn_mfma<<<dim3(32, BATCH * NH), 256, 0, stream>>>(Qb, Kb, Vt, ctx);
    convert_rows<<<BATCH * TSEQ, 256, 0, stream>>>(ctx, Chi, Clo, osq);
    gemm_yat_mfma<<<dim3(CDIM / 64, (BATCH * TSEQ) / 128), 256, 0, stream>>>(
        Chi, Clo, Wphi, Wplo, b_proj, osq, ksq + N3C, a_proj, outp,
        BATCH * TSEQ, CDIM, CDIM, (float)CDIM);
}

// Round 6
// 369.731 us; speedup vs baseline: 1.1336x; 1.1336x over previous
//
#include <hip/hip_runtime.h>
#include <math.h>

#define TSEQ  2048
#define BATCH 2
#define NH    16
#define HD    64
#define CDIM  1024
#define N3C   3072
#define EPSY  1e-6f

typedef unsigned short u16;
typedef unsigned int u32;
typedef __attribute__((ext_vector_type(8))) short bf16x8;
typedef __attribute__((ext_vector_type(4))) float f32x4;

#define MFMA16(a, b, c) __builtin_amdgcn_mfma_f32_16x16x32_bf16(a, b, c, 0, 0, 0)

__device__ __forceinline__ u16 f2bf(float f) {
    unsigned u = __float_as_uint(f);
    return (u16)((u + 0x7fffu + ((u >> 16) & 1u)) >> 16);
}
__device__ __forceinline__ float bf2f(u16 h) {
    return __uint_as_float(((unsigned)h) << 16);
}
__device__ __forceinline__ void gload16(const void* g, void* l) {
    __builtin_amdgcn_global_load_lds(
        (const __attribute__((address_space(1))) unsigned int*)g,
        (__attribute__((address_space(3))) unsigned int*)l, 16, 0, 0);
}

// ---------------------------------------------------------------------------
__global__ void rope_init(float2* __restrict__ sc) {
    int idx = blockIdx.x * 256 + threadIdx.x;   // 2048*32
    int t = idx >> 5, j = idx & 31;
    float inv = exp2f(-(float)j * 0.4152410118609203f);  // 10000^(-2j/64)
    float ang = (float)t * inv;
    sc[idx] = make_float2(cosf(ang), sinf(ang));
}

// ---------------------------------------------------------------------------
__global__ void colsq_kernel(const float* __restrict__ wa,
                             const float* __restrict__ wp,
                             float* __restrict__ ks) {
    int bid = blockIdx.x, tid = threadIdx.x;
    int c = tid & 63, kq = tid >> 6;
    const float* W; int N, col, outoff;
    if (bid < 48) { W = wa; N = N3C;  col = bid * 64 + c;        outoff = 0;   }
    else          { W = wp; N = CDIM; col = (bid - 48) * 64 + c; outoff = N3C; }
    float s = 0.f;
    int i0 = kq * 256;
    #pragma unroll 4
    for (int i = i0; i < i0 + 256; ++i) {
        float v = W[(size_t)i * N + col];
        s = fmaf(v, v, s);
    }
    __shared__ float red[256];
    red[tid] = s;
    __syncthreads();
    if (kq == 0) ks[outoff + col] = red[c] + red[64 + c] + red[128 + c] + red[192 + c];
}

// ---------------------------------------------------------------------------
__global__ void convert_rows(const float* __restrict__ X, u16* __restrict__ Xhi,
                             u16* __restrict__ Xlo, float* __restrict__ rsq) {
    int row = blockIdx.x, tid = threadIdx.x;
    int lane = tid & 63, wv = tid >> 6;
    size_t base = (size_t)row * CDIM + tid * 4;
    float4 v = *(const float4*)(X + base);
    ushort4 hi, lo;
    hi.x = f2bf(v.x); lo.x = f2bf(v.x - bf2f(hi.x));
    hi.y = f2bf(v.y); lo.y = f2bf(v.y - bf2f(hi.y));
    hi.z = f2bf(v.z); lo.z = f2bf(v.z - bf2f(hi.z));
    hi.w = f2bf(v.w); lo.w = f2bf(v.w - bf2f(hi.w));
    *(ushort4*)(Xhi + base) = hi;
    *(ushort4*)(Xlo + base) = lo;
    float s = v.x * v.x + v.y * v.y + v.z * v.z + v.w * v.w;
    #pragma unroll
    for (int off = 32; off; off >>= 1) s += __shfl_down(s, off, 64);
    __shared__ float red[4];
    if (lane == 0) red[wv] = s;
    __syncthreads();
    if (tid == 0) rsq[row] = red[0] + red[1] + red[2] + red[3];
}

// ---------------------------------------------------------------------------
__global__ void convert_wT(const float* __restrict__ W, u16* __restrict__ Whi,
                           u16* __restrict__ Wlo, int K, int N) {
    __shared__ float tile[64][68];
    int k0 = blockIdx.y * 64, n0 = blockIdx.x * 64;
    int tid = threadIdx.x;
    int r = tid >> 4, c4 = (tid & 15) * 4;
    #pragma unroll
    for (int i = 0; i < 4; ++i) {
        int k = k0 + r + i * 16;
        float4 v = *(const float4*)(W + (size_t)k * N + n0 + c4);
        *(float4*)&tile[r + i * 16][c4] = v;
    }
    __syncthreads();
    int n = tid >> 4, k4 = (tid & 15) * 4;
    #pragma unroll
    for (int i = 0; i < 4; ++i) {
        int nn = n + i * 16;
        float a = tile[k4 + 0][nn], b = tile[k4 + 1][nn];
        float c = tile[k4 + 2][nn], d = tile[k4 + 3][nn];
        ushort4 hi, lo;
        hi.x = f2bf(a); lo.x = f2bf(a - bf2f(hi.x));
        hi.y = f2bf(b); lo.y = f2bf(b - bf2f(hi.y));
        hi.z = f2bf(c); lo.z = f2bf(c - bf2f(hi.z));
        hi.w = f2bf(d); lo.w = f2bf(d - bf2f(hi.w));
        size_t o = (size_t)(n0 + nn) * K + k0 + k4;
        *(ushort4*)(Whi + o) = hi;
        *(ushort4*)(Wlo + o) = lo;
    }
}

// ---------------------------------------------------------------------------
// GEMM1: split-bf16 MFMA, yat epilogue fused with rotary (table) + bf16 pack.
// XOR-swizzled LDS staging (2-way max bank aliasing = free).
__global__ __launch_bounds__(256) void gemm1_fused(
    const u16* __restrict__ Ah, const u16* __restrict__ Al,
    const u16* __restrict__ Bh, const u16* __restrict__ Bl,
    const float* __restrict__ bias, const float* __restrict__ rowsq,
    const float* __restrict__ colsq, const float* __restrict__ alphap,
    const float2* __restrict__ ropeSC,
    u16* __restrict__ Qb, u16* __restrict__ Kb, u16* __restrict__ Vt) {
    constexpr int BK = 32;
    const int K = CDIM;
    __shared__ u16 Ash[128 * BK], Asl[128 * BK], Bsh[128 * BK], Bsl[128 * BK];
    int tid = threadIdx.x;
    int lane = tid & 63, wv = tid >> 6;
    int quad = lane >> 4, l15 = lane & 15;
    int wr = wv >> 1, wc = wv & 1;
    int bm = blockIdx.y * 128, bn = blockIdx.x * 128;
    int rsub = lane >> 2;
    int lc8 = (lane & 3) * 8;
    int gc8 = (((lane & 3) - (rsub >> 1)) & 3) * 8;
    int pf8 = ((quad + (l15 >> 1)) & 3) * 8;

    f32x4 acc[4][4];
    #pragma unroll
    for (int i = 0; i < 4; ++i)
        #pragma unroll
        for (int j = 0; j < 4; ++j) acc[i][j] = (f32x4){0.f, 0.f, 0.f, 0.f};

    for (int kt = 0; kt < K; kt += BK) {
        #pragma unroll
        for (int i = 0; i < 2; ++i) {
            int r = i * 64 + wv * 16 + rsub;
            size_t go = (size_t)(bm + r) * K + kt + gc8;
            gload16(Ah + go, &Ash[r * BK + lc8]);
            gload16(Al + go, &Asl[r * BK + lc8]);
            size_t gb = (size_t)(bn + r) * K + kt + gc8;
            gload16(Bh + gb, &Bsh[r * BK + lc8]);
            gload16(Bl + gb, &Bsl[r * BK + lc8]);
        }
        __syncthreads();
        bf16x8 fah[4], fal[4], fbh[4], fbl[4];
        #pragma unroll
        for (int i = 0; i < 4; ++i) {
            int r = wr * 64 + i * 16 + l15;
            fah[i] = *(const bf16x8*)&Ash[r * BK + pf8];
            fal[i] = *(const bf16x8*)&Asl[r * BK + pf8];
        }
        #pragma unroll
        for (int j = 0; j < 4; ++j) {
            int r = wc * 64 + j * 16 + l15;
            fbh[j] = *(const bf16x8*)&Bsh[r * BK + pf8];
            fbl[j] = *(const bf16x8*)&Bsl[r * BK + pf8];
        }
        #pragma unroll
        for (int i = 0; i < 4; ++i)
            #pragma unroll
            for (int j = 0; j < 4; ++j) {
                acc[i][j] = MFMA16(fah[i], fbh[j], acc[i][j]);
                acc[i][j] = MFMA16(fal[i], fbh[j], acc[i][j]);
                acc[i][j] = MFMA16(fah[i], fbl[j], acc[i][j]);
            }
        __syncthreads();
    }

    float alpha = alphap[0];
    float scale = powf(sqrtf((float)N3C) / logf(1.0f + (float)N3C), alpha);
    int segc0 = bn + wc * 64;          // wave-uniform
    int seg = segc0 >> 10;             // 0=Q 1=K 2=V
    int h = (segc0 >> 6) & 15;
    int bglob = bm >> 11;
    int bh = bglob * NH + h;

    if (seg < 2) {
        u16* dst = (seg == 0) ? Qb : Kb;
        float qs = (seg == 0) ? 0.125f : 1.0f;
        #pragma unroll
        for (int i = 0; i < 4; ++i) {
            int tb = bm + wr * 64 + i * 16 + quad * 4;
            #pragma unroll
            for (int r = 0; r < 4; ++r) {
                int row = tb + r;
                int t = row & (TSEQ - 1);
                float rs = rowsq[row];
                float y[4];
                #pragma unroll
                for (int j = 0; j < 4; ++j) {
                    int col = segc0 + j * 16 + l15;
                    float dot = acc[i][j][r];
                    float dist = rs + colsq[col] - 2.0f * dot + EPSY;
                    y[j] = dot * dot / dist * scale + bias[col];
                }
                float2 sc0 = ropeSC[t * 32 + l15];
                float2 sc1 = ropeSC[t * 32 + 16 + l15];
                float c0 = sc0.x, s0 = sc0.y, c1 = sc1.x, s1 = sc1.y;
                size_t ob = ((size_t)bh * TSEQ + t) * HD;
                dst[ob + l15]      = f2bf((y[0] * c0 - y[2] * s0) * qs);
                dst[ob + 16 + l15] = f2bf((y[1] * c1 - y[3] * s1) * qs);
                dst[ob + 32 + l15] = f2bf((y[2] * c0 + y[0] * s0) * qs);
                dst[ob + 48 + l15] = f2bf((y[3] * c1 + y[1] * s1) * qs);
            }
        }
    } else {
        #pragma unroll
        for (int i = 0; i < 4; ++i) {
            int tb = bm + wr * 64 + i * 16 + quad * 4;
            int t0 = tb & (TSEQ - 1);
            #pragma unroll
            for (int j = 0; j < 4; ++j) {
                int col = segc0 + j * 16 + l15;
                int d = j * 16 + l15;
                float cs = colsq[col], bi = bias[col];
                ushort4 pk;
                u16* pp = (u16*)&pk;
                #pragma unroll
                for (int r = 0; r < 4; ++r) {
                    float dot = acc[i][j][r];
                    float dist = rowsq[tb + r] + cs - 2.0f * dot + EPSY;
                    pp[r] = f2bf(dot * dot / dist * scale + bi);
                }
                *(ushort4*)(Vt + ((size_t)bh * HD + d) * TSEQ + t0) = pk;
            }
        }
    }
}

// ---------------------------------------------------------------------------
// GEMM2: split-bf16 MFMA + yat epilogue, fp32 out. (128x64 tile, swizzled LDS)
__global__ __launch_bounds__(256) void gemm_yat_mfma(
    const u16* __restrict__ Ah, const u16* __restrict__ Al,
    const u16* __restrict__ Bh, const u16* __restrict__ Bl,
    const float* __restrict__ bias, const float* __restrict__ rowsq,
    const float* __restrict__ colsq, const float* __restrict__ alphap,
    float* __restrict__ outp, int M, int N, int K, float outf) {
    constexpr int BM = 128, BN = 64, BK = 32;
    __shared__ u16 Ash[BM * BK], Asl[BM * BK], Bsh[BN * BK], Bsl[BN * BK];
    int tid = threadIdx.x;
    int lane = tid & 63, wv = tid >> 6;
    int quad = lane >> 4, l15 = lane & 15;
    int bm = blockIdx.y * BM, bn = blockIdx.x * BN;
    int rsub = lane >> 2;
    int lc8 = (lane & 3) * 8;
    int gc8 = (((lane & 3) - (rsub >> 1)) & 3) * 8;
    int pf8 = ((quad + (l15 >> 1)) & 3) * 8;

    f32x4 acc[2][4];
    #pragma unroll
    for (int i = 0; i < 2; ++i)
        #pragma unroll
        for (int j = 0; j < 4; ++j) acc[i][j] = (f32x4){0.f, 0.f, 0.f, 0.f};

    for (int kt = 0; kt < K; kt += BK) {
        #pragma unroll
        for (int i = 0; i < 2; ++i) {
            int r = i * 64 + wv * 16 + rsub;
            size_t go = (size_t)(bm + r) * K + kt + gc8;
            gload16(Ah + go, &Ash[r * BK + lc8]);
            gload16(Al + go, &Asl[r * BK + lc8]);
        }
        {
            int r = wv * 16 + rsub;
            size_t go = (size_t)(bn + r) * K + kt + gc8;
            gload16(Bh + go, &Bsh[r * BK + lc8]);
            gload16(Bl + go, &Bsl[r * BK + lc8]);
        }
        __syncthreads();
        bf16x8 fah[2], fal[2], fbh[4], fbl[4];
        #pragma unroll
        for (int i = 0; i < 2; ++i) {
            int r = wv * 32 + i * 16 + l15;
            fah[i] = *(const bf16x8*)&Ash[r * BK + pf8];
            fal[i] = *(const bf16x8*)&Asl[r * BK + pf8];
        }
        #pragma unroll
        for (int j = 0; j < 4; ++j) {
            int r = j * 16 + l15;
            fbh[j] = *(const bf16x8*)&Bsh[r * BK + pf8];
            fbl[j] = *(const bf16x8*)&Bsl[r * BK + pf8];
        }
        #pragma unroll
        for (int i = 0; i < 2; ++i)
            #pragma unroll
            for (int j = 0; j < 4; ++j) {
                acc[i][j] = MFMA16(fah[i], fbh[j], acc[i][j]);
                acc[i][j] = MFMA16(fal[i], fbh[j], acc[i][j]);
                acc[i][j] = MFMA16(fah[i], fbl[j], acc[i][j]);
            }
        __syncthreads();
    }

    float alpha = alphap[0];
    float scale = powf(sqrtf(outf) / logf(1.0f + outf), alpha);
    #pragma unroll
    for (int j = 0; j < 4; ++j) {
        int col = bn + j * 16 + l15;
        float cs = colsq[col], bi = bias[col];
        #pragma unroll
        for (int i = 0; i < 2; ++i) {
            #pragma unroll
            for (int r = 0; r < 4; ++r) {
                int row = bm + wv * 32 + i * 16 + quad * 4 + r;
                float dot = acc[i][j][r];
                float dist = rowsq[row] + cs - 2.0f * dot + EPSY;
                outp[(size_t)row * N + col] = dot * dot / dist * scale + bi;
            }
        }
    }
}

// ---------------------------------------------------------------------------
// S^T-formulation bf16 MFMA causal flash attention (R4 structure restored).
// 64-key tiles, grid (16, B*H), paired passes (qb, 31-qb) — balanced.
__global__ __launch_bounds__(256) void attn_mfma(
    const u16* __restrict__ Qb, const u16* __restrict__ Kb,
    const u16* __restrict__ Vt, float* __restrict__ ctx) {
    __shared__ u16 Ksh[64 * 64];   // [key][d-chunks, rotated by key]
    __shared__ u16 Vsh[64 * 64];   // [d][key-chunks, rotated by d]
    int tid = threadIdx.x;
    int lane = tid & 63, wv = tid >> 6;
    int quad = lane >> 4, l15 = lane & 15;
    int bh = blockIdx.y;
    int b = bh >> 4, h = bh & 15;
    const u16* Qh = Qb + (size_t)bh * TSEQ * HD;
    const u16* Kh = Kb + (size_t)bh * TSEQ * HD;
    const u16* Vh = Vt + (size_t)bh * HD * TSEQ;
    const f32x4 zf = {0.f, 0.f, 0.f, 0.f};

    for (int pass = 0; pass < 2; ++pass) {
        int qb = pass ? (31 - blockIdx.x) : blockIdx.x;
        int qw = qb * 64 + wv * 16;
        bf16x8 bq0 = *(const bf16x8*)(Qh + (size_t)(qw + l15) * HD + quad * 8);
        bf16x8 bq1 = *(const bf16x8*)(Qh + (size_t)(qw + l15) * HD + 32 + quad * 8);

        f32x4 o[4] = {zf, zf, zf, zf};
        float m = -1e30f, l = 0.f;

        for (int kt = 0; kt <= qb; ++kt) {
            int k0 = kt * 64;
            __syncthreads();
            #pragma unroll
            for (int p = 0; p < 2; ++p) {
                int lin = p * 256 + tid;
                int rowi = lin >> 3, ch = lin & 7;
                int gk = (ch + rowi) & 7;
                gload16(Kh + (size_t)(k0 + rowi) * HD + gk * 8, &Ksh[lin * 8]);
                gload16(Vh + (size_t)rowi * TSEQ + k0 + gk * 8, &Vsh[lin * 8]);
            }
            __syncthreads();

            f32x4 st[4];
            #pragma unroll
            for (int mt = 0; mt < 4; ++mt) {
                int key = mt * 16 + l15;
                bf16x8 a0 = *(const bf16x8*)&Ksh[key * 64 + ((quad - key) & 7) * 8];
                bf16x8 a1 = *(const bf16x8*)&Ksh[key * 64 + ((4 + quad - key) & 7) * 8];
                st[mt] = MFMA16(a0, bq0, zf);
                st[mt] = MFMA16(a1, bq1, st[mt]);
            }
            if (kt == qb) {
                int q = qw + l15;
                #pragma unroll
                for (int mt = 0; mt < 4; ++mt)
                    #pragma unroll
                    for (int r = 0; r < 4; ++r)
                        if (k0 + mt * 16 + quad * 4 + r > q) st[mt][r] = -1e30f;
            }
            float mx = -1e30f;
            #pragma unroll
            for (int mt = 0; mt < 4; ++mt)
                #pragma unroll
                for (int r = 0; r < 4; ++r) mx = fmaxf(mx, st[mt][r]);
            mx = fmaxf(mx, __shfl_xor(mx, 16, 64));
            mx = fmaxf(mx, __shfl_xor(mx, 32, 64));
            float mn = fmaxf(m, mx);
            float al = __expf(m - mn);
            m = mn;
            float ps = 0.f;
            u32 pp[4][2];
            #pragma unroll
            for (int mt = 0; mt < 4; ++mt) {
                float p0 = __expf(st[mt][0] - mn);
                float p1 = __expf(st[mt][1] - mn);
                float p2 = __expf(st[mt][2] - mn);
                float p3 = __expf(st[mt][3] - mn);
                ps += (p0 + p1) + (p2 + p3);
                pp[mt][0] = (u32)f2bf(p0) | ((u32)f2bf(p1) << 16);
                pp[mt][1] = (u32)f2bf(p2) | ((u32)f2bf(p3) << 16);
            }
            ps += __shfl_xor(ps, 16, 64);
            ps += __shfl_xor(ps, 32, 64);
            l = l * al + ps;
            #pragma unroll
            for (int dt = 0; dt < 4; ++dt) {
                o[dt][0] *= al; o[dt][1] *= al; o[dt][2] *= al; o[dt][3] *= al;
            }
            // PV: shuffle BOTH mt-candidates, select on the DESTINATION side.
            #pragma unroll
            for (int s = 0; s < 2; ++s) {
                u32 bw[4];
                #pragma unroll
                for (int w = 0; w < 4; ++w) {
                    int srcl = (((quad & 1) * 2 + (w >> 1)) << 4) + l15;
                    u32 vlo = (u32)__shfl((int)pp[2 * s][w & 1], srcl, 64);
                    u32 vhi = (u32)__shfl((int)pp[2 * s + 1][w & 1], srcl, 64);
                    bw[w] = (quad & 2) ? vhi : vlo;
                }
                bf16x8 bfr;
                *(u32*)&((short*)&bfr)[0] = bw[0];
                *(u32*)&((short*)&bfr)[2] = bw[1];
                *(u32*)&((short*)&bfr)[4] = bw[2];
                *(u32*)&((short*)&bfr)[6] = bw[3];
                #pragma unroll
                for (int dt = 0; dt < 4; ++dt) {
                    int d = dt * 16 + l15;
                    bf16x8 av = *(const bf16x8*)&Vsh[d * 64 + ((s * 4 + quad - d) & 7) * 8];
                    o[dt] = MFMA16(av, bfr, o[dt]);
                }
            }
        }

        float inv = 1.0f / l;
        #pragma unroll
        for (int dt = 0; dt < 4; ++dt) {
            float4 r;
            r.x = o[dt][0] * inv; r.y = o[dt][1] * inv;
            r.z = o[dt][2] * inv; r.w = o[dt][3] * inv;
            *(float4*)(ctx + ((size_t)b * TSEQ + qw + l15) * CDIM
                       + h * HD + dt * 16 + quad * 4) = r;
        }
    }
}

// ---------------------------------------------------------------------------
extern "C" void kernel_launch(void* const* d_in, const int* in_sizes, int n_in,
                              void* d_out, int out_size, void* d_ws, size_t ws_size,
                              hipStream_t stream) {
    const float* x      = (const float*)d_in[0];
    const float* w_attn = (const float*)d_in[2];
    const float* b_attn = (const float*)d_in[3];
    const float* a_attn = (const float*)d_in[4];
    const float* w_proj = (const float*)d_in[5];
    const float* b_proj = (const float*)d_in[6];
    const float* a_proj = (const float*)d_in[7];
    float* outp = (float*)d_out;

    char* ws = (char*)d_ws;
    float* ksq = (float*)(ws);
    float* xsq = (float*)(ws + 16384);
    float* osq = (float*)(ws + 32768);
    char* pA  = ws + 65536;                    // 16.78 MB: Ahi/Alo -> ctx
    u16* Ahi = (u16*)pA;
    u16* Alo = (u16*)(pA + 8388608);
    float* ctx = (float*)pA;                   // alias (A dead after GEMM1)
    char* pWt = pA + 16777216;                 // 12.58 MB
    u16* Wthi = (u16*)pWt;
    u16* Wtlo = (u16*)(pWt + 6291456);
    char* pWp = pWt + 12582912;                // 4.19 MB
    u16* Wphi = (u16*)pWp;
    u16* Wplo = (u16*)(pWp + 2097152);
    char* pQ = pWp + 4194304;                  // 25.17 MB: Qb,Kb,Vt
    u16* Qb = (u16*)pQ;
    u16* Kb = (u16*)(pQ + 8388608);
    u16* Vt = (u16*)(pQ + 16777216);
    u16* Chi = (u16*)pQ;                       // alias (Q/K dead after attn)
    u16* Clo = (u16*)(pQ + 8388608);
    float2* ropeSC = (float2*)(pQ + 25165824); // 512 KB, ends ~59.3 MB

    rope_init<<<256, 256, 0, stream>>>(ropeSC);
    colsq_kernel<<<64, 256, 0, stream>>>(w_attn, w_proj, ksq);
    convert_rows<<<BATCH * TSEQ, 256, 0, stream>>>(x, Ahi, Alo, xsq);
    convert_wT<<<dim3(N3C / 64, CDIM / 64), 256, 0, stream>>>(w_attn, Wthi, Wtlo, CDIM, N3C);
    convert_wT<<<dim3(CDIM / 64, CDIM / 64), 256, 0, stream>>>(w_proj, Wphi, Wplo, CDIM, CDIM);
    gemm1_fused<<<dim3(N3C / 128, (BATCH * TSEQ) / 128), 256, 0, stream>>>(
        Ahi, Alo, Wthi, Wtlo, b_attn, xsq, ksq, a_attn, ropeSC, Qb, Kb, Vt);
    attn_mfma<<<dim3(16, BATCH * NH), 256, 0, stream>>>(Qb, Kb, Vt, ctx);
    convert_rows<<<BATCH * TSEQ, 256, 0, stream>>>(ctx, Chi, Clo, osq);
    gemm_yat_mfma<<<dim3(CDIM / 64, (BATCH * TSEQ) / 128), 256, 0, stream>>>(
        Chi, Clo, Wphi, Wplo, b_proj, osq, ksq + N3C, a_proj, outp,
        BATCH * TSEQ, CDIM, CDIM, (float)CDIM);
}

// Round 7
// 281.004 us; speedup vs baseline: 1.4915x; 1.3158x over previous
//
#include <hip/hip_runtime.h>
#include <math.h>

#define TSEQ  2048
#define BATCH 2
#define NH    16
#define HD    64
#define CDIM  1024
#define N3C   3072
#define EPSY  1e-6f

typedef unsigned short u16;
typedef unsigned int u32;
typedef __attribute__((ext_vector_type(8))) short bf16x8;
typedef __attribute__((ext_vector_type(4))) float f32x4;

#define MFMA16(a, b, c) __builtin_amdgcn_mfma_f32_16x16x32_bf16(a, b, c, 0, 0, 0)

__device__ __forceinline__ u16 f2bf(float f) {
    unsigned u = __float_as_uint(f);
    return (u16)((u + 0x7fffu + ((u >> 16) & 1u)) >> 16);
}
__device__ __forceinline__ float bf2f(u16 h) {
    return __uint_as_float(((unsigned)h) << 16);
}
__device__ __forceinline__ void gload16(const void* g, void* l) {
    __builtin_amdgcn_global_load_lds(
        (const __attribute__((address_space(1))) unsigned int*)g,
        (__attribute__((address_space(3))) unsigned int*)l, 16, 0, 0);
}

// ---------------------------------------------------------------------------
__global__ void rope_init(float2* __restrict__ sc) {
    int idx = blockIdx.x * 256 + threadIdx.x;   // 2048*32
    int t = idx >> 5, j = idx & 31;
    float inv = exp2f(-(float)j * 0.4152410118609203f);  // 10000^(-2j/64)
    float ang = (float)t * inv;
    sc[idx] = make_float2(cosf(ang), sinf(ang));
}

// ---------------------------------------------------------------------------
__global__ void colsq_kernel(const float* __restrict__ wa,
                             const float* __restrict__ wp,
                             float* __restrict__ ks) {
    int bid = blockIdx.x, tid = threadIdx.x;
    int c = tid & 63, kq = tid >> 6;
    const float* W; int N, col, outoff;
    if (bid < 48) { W = wa; N = N3C;  col = bid * 64 + c;        outoff = 0;   }
    else          { W = wp; N = CDIM; col = (bid - 48) * 64 + c; outoff = N3C; }
    float s = 0.f;
    int i0 = kq * 256;
    #pragma unroll 4
    for (int i = i0; i < i0 + 256; ++i) {
        float v = W[(size_t)i * N + col];
        s = fmaf(v, v, s);
    }
    __shared__ float red[256];
    red[tid] = s;
    __syncthreads();
    if (kq == 0) ks[outoff + col] = red[c] + red[64 + c] + red[128 + c] + red[192 + c];
}

// ---------------------------------------------------------------------------
// Xlo may be null (hi-only mode: GEMM1 inputs are single-bf16).
__global__ void convert_rows(const float* __restrict__ X, u16* __restrict__ Xhi,
                             u16* __restrict__ Xlo, float* __restrict__ rsq) {
    int row = blockIdx.x, tid = threadIdx.x;
    int lane = tid & 63, wv = tid >> 6;
    size_t base = (size_t)row * CDIM + tid * 4;
    float4 v = *(const float4*)(X + base);
    ushort4 hi;
    hi.x = f2bf(v.x); hi.y = f2bf(v.y); hi.z = f2bf(v.z); hi.w = f2bf(v.w);
    *(ushort4*)(Xhi + base) = hi;
    if (Xlo) {
        ushort4 lo;
        lo.x = f2bf(v.x - bf2f(hi.x));
        lo.y = f2bf(v.y - bf2f(hi.y));
        lo.z = f2bf(v.z - bf2f(hi.z));
        lo.w = f2bf(v.w - bf2f(hi.w));
        *(ushort4*)(Xlo + base) = lo;
    }
    float s = v.x * v.x + v.y * v.y + v.z * v.z + v.w * v.w;
    #pragma unroll
    for (int off = 32; off; off >>= 1) s += __shfl_down(s, off, 64);
    __shared__ float red[4];
    if (lane == 0) red[wv] = s;
    __syncthreads();
    if (tid == 0) rsq[row] = red[0] + red[1] + red[2] + red[3];
}

// ---------------------------------------------------------------------------
// Wlo may be null (hi-only mode for w_attn).
__global__ void convert_wT(const float* __restrict__ W, u16* __restrict__ Whi,
                           u16* __restrict__ Wlo, int K, int N) {
    __shared__ float tile[64][68];
    int k0 = blockIdx.y * 64, n0 = blockIdx.x * 64;
    int tid = threadIdx.x;
    int r = tid >> 4, c4 = (tid & 15) * 4;
    #pragma unroll
    for (int i = 0; i < 4; ++i) {
        int k = k0 + r + i * 16;
        float4 v = *(const float4*)(W + (size_t)k * N + n0 + c4);
        *(float4*)&tile[r + i * 16][c4] = v;
    }
    __syncthreads();
    int n = tid >> 4, k4 = (tid & 15) * 4;
    #pragma unroll
    for (int i = 0; i < 4; ++i) {
        int nn = n + i * 16;
        float a = tile[k4 + 0][nn], b = tile[k4 + 1][nn];
        float c = tile[k4 + 2][nn], d = tile[k4 + 3][nn];
        ushort4 hi;
        hi.x = f2bf(a); hi.y = f2bf(b); hi.z = f2bf(c); hi.w = f2bf(d);
        size_t o = (size_t)(n0 + nn) * K + k0 + k4;
        *(ushort4*)(Whi + o) = hi;
        if (Wlo) {
            ushort4 lo;
            lo.x = f2bf(a - bf2f(hi.x));
            lo.y = f2bf(b - bf2f(hi.y));
            lo.z = f2bf(c - bf2f(hi.z));
            lo.w = f2bf(d - bf2f(hi.w));
            *(ushort4*)(Wlo + o) = lo;
        }
    }
}

// ---------------------------------------------------------------------------
// GEMM1: SINGLE-bf16 MFMA (outputs are bf16-rounded anyway — lo terms are
// below the downstream rounding floor). yat epilogue + rotary table + pack.
// XOR-swizzled LDS staging (0 bank conflicts, verified R6).
// __launch_bounds__(256,4): pin 4 blocks/CU (R6 regression: VGPR 136 -> 3).
__global__ __launch_bounds__(256, 4) void gemm1_fused(
    const u16* __restrict__ Ah, const u16* __restrict__ Bh,
    const float* __restrict__ bias, const float* __restrict__ rowsq,
    const float* __restrict__ colsq, const float* __restrict__ alphap,
    const float2* __restrict__ ropeSC,
    u16* __restrict__ Qb, u16* __restrict__ Kb, u16* __restrict__ Vt) {
    constexpr int BK = 32;
    const int K = CDIM;
    __shared__ u16 Ash[128 * BK], Bsh[128 * BK];
    int tid = threadIdx.x;
    int lane = tid & 63, wv = tid >> 6;
    int quad = lane >> 4, l15 = lane & 15;
    int wr = wv >> 1, wc = wv & 1;
    int bm = blockIdx.y * 128, bn = blockIdx.x * 128;
    int rsub = lane >> 2;
    int lc8 = (lane & 3) * 8;
    int gc8 = (((lane & 3) - (rsub >> 1)) & 3) * 8;
    int pf8 = ((quad + (l15 >> 1)) & 3) * 8;

    f32x4 acc[4][4];
    #pragma unroll
    for (int i = 0; i < 4; ++i)
        #pragma unroll
        for (int j = 0; j < 4; ++j) acc[i][j] = (f32x4){0.f, 0.f, 0.f, 0.f};

    for (int kt = 0; kt < K; kt += BK) {
        #pragma unroll
        for (int i = 0; i < 2; ++i) {
            int r = i * 64 + wv * 16 + rsub;
            gload16(Ah + (size_t)(bm + r) * K + kt + gc8, &Ash[r * BK + lc8]);
            gload16(Bh + (size_t)(bn + r) * K + kt + gc8, &Bsh[r * BK + lc8]);
        }
        __syncthreads();
        bf16x8 fah[4], fbh[4];
        #pragma unroll
        for (int i = 0; i < 4; ++i) {
            int r = wr * 64 + i * 16 + l15;
            fah[i] = *(const bf16x8*)&Ash[r * BK + pf8];
        }
        #pragma unroll
        for (int j = 0; j < 4; ++j) {
            int r = wc * 64 + j * 16 + l15;
            fbh[j] = *(const bf16x8*)&Bsh[r * BK + pf8];
        }
        #pragma unroll
        for (int i = 0; i < 4; ++i)
            #pragma unroll
            for (int j = 0; j < 4; ++j)
                acc[i][j] = MFMA16(fah[i], fbh[j], acc[i][j]);
        __syncthreads();
    }

    float alpha = alphap[0];
    float scale = powf(sqrtf((float)N3C) / logf(1.0f + (float)N3C), alpha);
    int segc0 = bn + wc * 64;          // wave-uniform
    int seg = segc0 >> 10;             // 0=Q 1=K 2=V
    int h = (segc0 >> 6) & 15;
    int bglob = bm >> 11;
    int bh = bglob * NH + h;

    if (seg < 2) {
        u16* dst = (seg == 0) ? Qb : Kb;
        float qs = (seg == 0) ? 0.125f : 1.0f;
        #pragma unroll
        for (int i = 0; i < 4; ++i) {
            int tb = bm + wr * 64 + i * 16 + quad * 4;
            #pragma unroll
            for (int r = 0; r < 4; ++r) {
                int row = tb + r;
                int t = row & (TSEQ - 1);
                float rs = rowsq[row];
                float y[4];
                #pragma unroll
                for (int j = 0; j < 4; ++j) {
                    int col = segc0 + j * 16 + l15;
                    float dot = acc[i][j][r];
                    float dist = rs + colsq[col] - 2.0f * dot + EPSY;
                    y[j] = dot * dot / dist * scale + bias[col];
                }
                float2 sc0 = ropeSC[t * 32 + l15];
                float2 sc1 = ropeSC[t * 32 + 16 + l15];
                float c0 = sc0.x, s0 = sc0.y, c1 = sc1.x, s1 = sc1.y;
                size_t ob = ((size_t)bh * TSEQ + t) * HD;
                dst[ob + l15]      = f2bf((y[0] * c0 - y[2] * s0) * qs);
                dst[ob + 16 + l15] = f2bf((y[1] * c1 - y[3] * s1) * qs);
                dst[ob + 32 + l15] = f2bf((y[2] * c0 + y[0] * s0) * qs);
                dst[ob + 48 + l15] = f2bf((y[3] * c1 + y[1] * s1) * qs);
            }
        }
    } else {
        #pragma unroll
        for (int i = 0; i < 4; ++i) {
            int tb = bm + wr * 64 + i * 16 + quad * 4;
            int t0 = tb & (TSEQ - 1);
            #pragma unroll
            for (int j = 0; j < 4; ++j) {
                int col = segc0 + j * 16 + l15;
                int d = j * 16 + l15;
                float cs = colsq[col], bi = bias[col];
                ushort4 pk;
                u16* pp = (u16*)&pk;
                #pragma unroll
                for (int r = 0; r < 4; ++r) {
                    float dot = acc[i][j][r];
                    float dist = rowsq[tb + r] + cs - 2.0f * dot + EPSY;
                    pp[r] = f2bf(dot * dot / dist * scale + bi);
                }
                *(ushort4*)(Vt + ((size_t)bh * HD + d) * TSEQ + t0) = pk;
            }
        }
    }
}

// ---------------------------------------------------------------------------
// GEMM2: split-bf16 3-product MFMA + yat epilogue, fp32 out (final output —
// needs the precision). 128x64 tile, swizzled LDS, 4 blocks/CU pinned.
__global__ __launch_bounds__(256, 4) void gemm_yat_mfma(
    const u16* __restrict__ Ah, const u16* __restrict__ Al,
    const u16* __restrict__ Bh, const u16* __restrict__ Bl,
    const float* __restrict__ bias, const float* __restrict__ rowsq,
    const float* __restrict__ colsq, const float* __restrict__ alphap,
    float* __restrict__ outp, int M, int N, int K, float outf) {
    constexpr int BM = 128, BN = 64, BK = 32;
    __shared__ u16 Ash[BM * BK], Asl[BM * BK], Bsh[BN * BK], Bsl[BN * BK];
    int tid = threadIdx.x;
    int lane = tid & 63, wv = tid >> 6;
    int quad = lane >> 4, l15 = lane & 15;
    int bm = blockIdx.y * BM, bn = blockIdx.x * BN;
    int rsub = lane >> 2;
    int lc8 = (lane & 3) * 8;
    int gc8 = (((lane & 3) - (rsub >> 1)) & 3) * 8;
    int pf8 = ((quad + (l15 >> 1)) & 3) * 8;

    f32x4 acc[2][4];
    #pragma unroll
    for (int i = 0; i < 2; ++i)
        #pragma unroll
        for (int j = 0; j < 4; ++j) acc[i][j] = (f32x4){0.f, 0.f, 0.f, 0.f};

    for (int kt = 0; kt < K; kt += BK) {
        #pragma unroll
        for (int i = 0; i < 2; ++i) {
            int r = i * 64 + wv * 16 + rsub;
            size_t go = (size_t)(bm + r) * K + kt + gc8;
            gload16(Ah + go, &Ash[r * BK + lc8]);
            gload16(Al + go, &Asl[r * BK + lc8]);
        }
        {
            int r = wv * 16 + rsub;
            size_t go = (size_t)(bn + r) * K + kt + gc8;
            gload16(Bh + go, &Bsh[r * BK + lc8]);
            gload16(Bl + go, &Bsl[r * BK + lc8]);
        }
        __syncthreads();
        bf16x8 fah[2], fal[2], fbh[4], fbl[4];
        #pragma unroll
        for (int i = 0; i < 2; ++i) {
            int r = wv * 32 + i * 16 + l15;
            fah[i] = *(const bf16x8*)&Ash[r * BK + pf8];
            fal[i] = *(const bf16x8*)&Asl[r * BK + pf8];
        }
        #pragma unroll
        for (int j = 0; j < 4; ++j) {
            int r = j * 16 + l15;
            fbh[j] = *(const bf16x8*)&Bsh[r * BK + pf8];
            fbl[j] = *(const bf16x8*)&Bsl[r * BK + pf8];
        }
        #pragma unroll
        for (int i = 0; i < 2; ++i)
            #pragma unroll
            for (int j = 0; j < 4; ++j) {
                acc[i][j] = MFMA16(fah[i], fbh[j], acc[i][j]);
                acc[i][j] = MFMA16(fal[i], fbh[j], acc[i][j]);
                acc[i][j] = MFMA16(fah[i], fbl[j], acc[i][j]);
            }
        __syncthreads();
    }

    float alpha = alphap[0];
    float scale = powf(sqrtf(outf) / logf(1.0f + outf), alpha);
    #pragma unroll
    for (int j = 0; j < 4; ++j) {
        int col = bn + j * 16 + l15;
        float cs = colsq[col], bi = bias[col];
        #pragma unroll
        for (int i = 0; i < 2; ++i) {
            #pragma unroll
            for (int r = 0; r < 4; ++r) {
                int row = bm + wv * 32 + i * 16 + quad * 4 + r;
                float dot = acc[i][j][r];
                float dist = rowsq[row] + cs - 2.0f * dot + EPSY;
                outp[(size_t)row * N + col] = dot * dot / dist * scale + bi;
            }
        }
    }
}

// ---------------------------------------------------------------------------
// S^T-formulation bf16 MFMA causal flash attention (R4 structure).
// 64-key tiles, grid (16, B*H), paired passes (qb, 31-qb) — balanced.
__global__ __launch_bounds__(256) void attn_mfma(
    const u16* __restrict__ Qb, const u16* __restrict__ Kb,
    const u16* __restrict__ Vt, float* __restrict__ ctx) {
    __shared__ u16 Ksh[64 * 64];   // [key][d-chunks, rotated by key]
    __shared__ u16 Vsh[64 * 64];   // [d][key-chunks, rotated by d]
    int tid = threadIdx.x;
    int lane = tid & 63, wv = tid >> 6;
    int quad = lane >> 4, l15 = lane & 15;
    int bh = blockIdx.y;
    int b = bh >> 4, h = bh & 15;
    const u16* Qh = Qb + (size_t)bh * TSEQ * HD;
    const u16* Kh = Kb + (size_t)bh * TSEQ * HD;
    const u16* Vh = Vt + (size_t)bh * HD * TSEQ;
    const f32x4 zf = {0.f, 0.f, 0.f, 0.f};

    for (int pass = 0; pass < 2; ++pass) {
        int qb = pass ? (31 - blockIdx.x) : blockIdx.x;
        int qw = qb * 64 + wv * 16;
        bf16x8 bq0 = *(const bf16x8*)(Qh + (size_t)(qw + l15) * HD + quad * 8);
        bf16x8 bq1 = *(const bf16x8*)(Qh + (size_t)(qw + l15) * HD + 32 + quad * 8);

        f32x4 o[4] = {zf, zf, zf, zf};
        float m = -1e30f, l = 0.f;

        for (int kt = 0; kt <= qb; ++kt) {
            int k0 = kt * 64;
            __syncthreads();
            #pragma unroll
            for (int p = 0; p < 2; ++p) {
                int lin = p * 256 + tid;
                int rowi = lin >> 3, ch = lin & 7;
                int gk = (ch + rowi) & 7;
                gload16(Kh + (size_t)(k0 + rowi) * HD + gk * 8, &Ksh[lin * 8]);
                gload16(Vh + (size_t)rowi * TSEQ + k0 + gk * 8, &Vsh[lin * 8]);
            }
            __syncthreads();

            f32x4 st[4];
            #pragma unroll
            for (int mt = 0; mt < 4; ++mt) {
                int key = mt * 16 + l15;
                bf16x8 a0 = *(const bf16x8*)&Ksh[key * 64 + ((quad - key) & 7) * 8];
                bf16x8 a1 = *(const bf16x8*)&Ksh[key * 64 + ((4 + quad - key) & 7) * 8];
                st[mt] = MFMA16(a0, bq0, zf);
                st[mt] = MFMA16(a1, bq1, st[mt]);
            }
            if (kt == qb) {
                int q = qw + l15;
                #pragma unroll
                for (int mt = 0; mt < 4; ++mt)
                    #pragma unroll
                    for (int r = 0; r < 4; ++r)
                        if (k0 + mt * 16 + quad * 4 + r > q) st[mt][r] = -1e30f;
            }
            float mx = -1e30f;
            #pragma unroll
            for (int mt = 0; mt < 4; ++mt)
                #pragma unroll
                for (int r = 0; r < 4; ++r) mx = fmaxf(mx, st[mt][r]);
            mx = fmaxf(mx, __shfl_xor(mx, 16, 64));
            mx = fmaxf(mx, __shfl_xor(mx, 32, 64));
            float mn = fmaxf(m, mx);
            float al = __expf(m - mn);
            m = mn;
            float ps = 0.f;
            u32 pp[4][2];
            #pragma unroll
            for (int mt = 0; mt < 4; ++mt) {
                float p0 = __expf(st[mt][0] - mn);
                float p1 = __expf(st[mt][1] - mn);
                float p2 = __expf(st[mt][2] - mn);
                float p3 = __expf(st[mt][3] - mn);
                ps += (p0 + p1) + (p2 + p3);
                pp[mt][0] = (u32)f2bf(p0) | ((u32)f2bf(p1) << 16);
                pp[mt][1] = (u32)f2bf(p2) | ((u32)f2bf(p3) << 16);
            }
            ps += __shfl_xor(ps, 16, 64);
            ps += __shfl_xor(ps, 32, 64);
            l = l * al + ps;
            #pragma unroll
            for (int dt = 0; dt < 4; ++dt) {
                o[dt][0] *= al; o[dt][1] *= al; o[dt][2] *= al; o[dt][3] *= al;
            }
            // PV: shuffle BOTH mt-candidates, select on the DESTINATION side.
            #pragma unroll
            for (int s = 0; s < 2; ++s) {
                u32 bw[4];
                #pragma unroll
                for (int w = 0; w < 4; ++w) {
                    int srcl = (((quad & 1) * 2 + (w >> 1)) << 4) + l15;
                    u32 vlo = (u32)__shfl((int)pp[2 * s][w & 1], srcl, 64);
                    u32 vhi = (u32)__shfl((int)pp[2 * s + 1][w & 1], srcl, 64);
                    bw[w] = (quad & 2) ? vhi : vlo;
                }
                bf16x8 bfr;
                *(u32*)&((short*)&bfr)[0] = bw[0];
                *(u32*)&((short*)&bfr)[2] = bw[1];
                *(u32*)&((short*)&bfr)[4] = bw[2];
                *(u32*)&((short*)&bfr)[6] = bw[3];
                #pragma unroll
                for (int dt = 0; dt < 4; ++dt) {
                    int d = dt * 16 + l15;
                    bf16x8 av = *(const bf16x8*)&Vsh[d * 64 + ((s * 4 + quad - d) & 7) * 8];
                    o[dt] = MFMA16(av, bfr, o[dt]);
                }
            }
        }

        float inv = 1.0f / l;
        #pragma unroll
        for (int dt = 0; dt < 4; ++dt) {
            float4 r;
            r.x = o[dt][0] * inv; r.y = o[dt][1] * inv;
            r.z = o[dt][2] * inv; r.w = o[dt][3] * inv;
            *(float4*)(ctx + ((size_t)b * TSEQ + qw + l15) * CDIM
                       + h * HD + dt * 16 + quad * 4) = r;
        }
    }
}

// ---------------------------------------------------------------------------
extern "C" void kernel_launch(void* const* d_in, const int* in_sizes, int n_in,
                              void* d_out, int out_size, void* d_ws, size_t ws_size,
                              hipStream_t stream) {
    const float* x      = (const float*)d_in[0];
    const float* w_attn = (const float*)d_in[2];
    const float* b_attn = (const float*)d_in[3];
    const float* a_attn = (const float*)d_in[4];
    const float* w_proj = (const float*)d_in[5];
    const float* b_proj = (const float*)d_in[6];
    const float* a_proj = (const float*)d_in[7];
    float* outp = (float*)d_out;

    char* ws = (char*)d_ws;
    float* ksq = (float*)(ws);
    float* xsq = (float*)(ws + 16384);
    float* osq = (float*)(ws + 32768);
    char* pA  = ws + 65536;                    // 16.78 MB: Ahi -> ctx
    u16* Ahi = (u16*)pA;
    float* ctx = (float*)pA;                   // alias (A dead after GEMM1)
    char* pWt = pA + 16777216;                 // 6.29 MB (hi only)
    u16* Wthi = (u16*)pWt;
    char* pWp = pWt + 6291456;                 // 4.19 MB
    u16* Wphi = (u16*)pWp;
    u16* Wplo = (u16*)(pWp + 2097152);
    char* pQ = pWp + 4194304;                  // 25.17 MB: Qb,Kb,Vt
    u16* Qb = (u16*)pQ;
    u16* Kb = (u16*)(pQ + 8388608);
    u16* Vt = (u16*)(pQ + 16777216);
    u16* Chi = (u16*)pQ;                       // alias (Q/K dead after attn)
    u16* Clo = (u16*)(pQ + 8388608);
    float2* ropeSC = (float2*)(pQ + 25165824); // 512 KB

    rope_init<<<256, 256, 0, stream>>>(ropeSC);
    colsq_kernel<<<64, 256, 0, stream>>>(w_attn, w_proj, ksq);
    convert_rows<<<BATCH * TSEQ, 256, 0, stream>>>(x, Ahi, (u16*)nullptr, xsq);
    convert_wT<<<dim3(N3C / 64, CDIM / 64), 256, 0, stream>>>(w_attn, Wthi, (u16*)nullptr, CDIM, N3C);
    convert_wT<<<dim3(CDIM / 64, CDIM / 64), 256, 0, stream>>>(w_proj, Wphi, Wplo, CDIM, CDIM);
    gemm1_fused<<<dim3(N3C / 128, (BATCH * TSEQ) / 128), 256, 0, stream>>>(
        Ahi, Wthi, b_attn, xsq, ksq, a_attn, ropeSC, Qb, Kb, Vt);
    attn_mfma<<<dim3(16, BATCH * NH), 256, 0, stream>>>(Qb, Kb, Vt, ctx);
    convert_rows<<<BATCH * TSEQ, 256, 0, stream>>>(ctx, Chi, Clo, osq);
    gemm_yat_mfma<<<dim3(CDIM / 64, (BATCH * TSEQ) / 128), 256, 0, stream>>>(
        Chi, Clo, Wphi, Wplo, b_proj, osq, ksq + N3C, a_proj, outp,
        BATCH * TSEQ, CDIM, CDIM, (float)CDIM);
}

// Round 8
// 269.998 us; speedup vs baseline: 1.5523x; 1.0408x over previous
//
#include <hip/hip_runtime.h>
#include <math.h>

#define TSEQ  2048
#define BATCH 2
#define NH    16
#define HD    64
#define CDIM  1024
#define N3C   3072
#define EPSY  1e-6f

typedef unsigned short u16;
typedef unsigned int u32;
typedef __attribute__((ext_vector_type(8))) short bf16x8;
typedef __attribute__((ext_vector_type(4))) float f32x4;

#define MFMA16(a, b, c) __builtin_amdgcn_mfma_f32_16x16x32_bf16(a, b, c, 0, 0, 0)

__device__ __forceinline__ u16 f2bf(float f) {
    unsigned u = __float_as_uint(f);
    return (u16)((u + 0x7fffu + ((u >> 16) & 1u)) >> 16);
}
__device__ __forceinline__ float bf2f(u16 h) {
    return __uint_as_float(((unsigned)h) << 16);
}
__device__ __forceinline__ void gload16(const void* g, void* l) {
    __builtin_amdgcn_global_load_lds(
        (const __attribute__((address_space(1))) unsigned int*)g,
        (__attribute__((address_space(3))) unsigned int*)l, 16, 0, 0);
}

// ---------------------------------------------------------------------------
__global__ void rope_init(float2* __restrict__ sc) {
    int idx = blockIdx.x * 256 + threadIdx.x;   // 2048*32
    int t = idx >> 5, j = idx & 31;
    float inv = exp2f(-(float)j * 0.4152410118609203f);  // 10000^(-2j/64)
    float ang = (float)t * inv;
    sc[idx] = make_float2(cosf(ang), sinf(ang));
}

// ---------------------------------------------------------------------------
__global__ void colsq_kernel(const float* __restrict__ wa,
                             const float* __restrict__ wp,
                             float* __restrict__ ks) {
    int bid = blockIdx.x, tid = threadIdx.x;
    int c = tid & 63, kq = tid >> 6;
    const float* W; int N, col, outoff;
    if (bid < 48) { W = wa; N = N3C;  col = bid * 64 + c;        outoff = 0;   }
    else          { W = wp; N = CDIM; col = (bid - 48) * 64 + c; outoff = N3C; }
    float s = 0.f;
    int i0 = kq * 256;
    #pragma unroll 4
    for (int i = i0; i < i0 + 256; ++i) {
        float v = W[(size_t)i * N + col];
        s = fmaf(v, v, s);
    }
    __shared__ float red[256];
    red[tid] = s;
    __syncthreads();
    if (kq == 0) ks[outoff + col] = red[c] + red[64 + c] + red[128 + c] + red[192 + c];
}

// ---------------------------------------------------------------------------
__global__ void convert_rows(const float* __restrict__ X, u16* __restrict__ Xhi,
                             float* __restrict__ rsq) {
    int row = blockIdx.x, tid = threadIdx.x;
    int lane = tid & 63, wv = tid >> 6;
    size_t base = (size_t)row * CDIM + tid * 4;
    float4 v = *(const float4*)(X + base);
    ushort4 hi;
    hi.x = f2bf(v.x); hi.y = f2bf(v.y); hi.z = f2bf(v.z); hi.w = f2bf(v.w);
    *(ushort4*)(Xhi + base) = hi;
    float s = v.x * v.x + v.y * v.y + v.z * v.z + v.w * v.w;
    #pragma unroll
    for (int off = 32; off; off >>= 1) s += __shfl_down(s, off, 64);
    __shared__ float red[4];
    if (lane == 0) red[wv] = s;
    __syncthreads();
    if (tid == 0) rsq[row] = red[0] + red[1] + red[2] + red[3];
}

// ---------------------------------------------------------------------------
__global__ void convert_wT(const float* __restrict__ W, u16* __restrict__ Whi,
                           int K, int N) {
    __shared__ float tile[64][68];
    int k0 = blockIdx.y * 64, n0 = blockIdx.x * 64;
    int tid = threadIdx.x;
    int r = tid >> 4, c4 = (tid & 15) * 4;
    #pragma unroll
    for (int i = 0; i < 4; ++i) {
        int k = k0 + r + i * 16;
        float4 v = *(const float4*)(W + (size_t)k * N + n0 + c4);
        *(float4*)&tile[r + i * 16][c4] = v;
    }
    __syncthreads();
    int n = tid >> 4, k4 = (tid & 15) * 4;
    #pragma unroll
    for (int i = 0; i < 4; ++i) {
        int nn = n + i * 16;
        ushort4 hi;
        hi.x = f2bf(tile[k4 + 0][nn]);
        hi.y = f2bf(tile[k4 + 1][nn]);
        hi.z = f2bf(tile[k4 + 2][nn]);
        hi.w = f2bf(tile[k4 + 3][nn]);
        *(ushort4*)(Whi + (size_t)(n0 + nn) * K + k0 + k4) = hi;
    }
}

// ---------------------------------------------------------------------------
// GEMM1: single-bf16 MFMA, yat epilogue + rotary table + bf16 pack.
// XOR-swizzled LDS staging (0 bank conflicts). 4 blocks/CU pinned.
__global__ __launch_bounds__(256, 4) void gemm1_fused(
    const u16* __restrict__ Ah, const u16* __restrict__ Bh,
    const float* __restrict__ bias, const float* __restrict__ rowsq,
    const float* __restrict__ colsq, const float* __restrict__ alphap,
    const float2* __restrict__ ropeSC,
    u16* __restrict__ Qb, u16* __restrict__ Kb, u16* __restrict__ Vt) {
    constexpr int BK = 32;
    const int K = CDIM;
    __shared__ u16 Ash[128 * BK], Bsh[128 * BK];
    int tid = threadIdx.x;
    int lane = tid & 63, wv = tid >> 6;
    int quad = lane >> 4, l15 = lane & 15;
    int wr = wv >> 1, wc = wv & 1;
    int bm = blockIdx.y * 128, bn = blockIdx.x * 128;
    int rsub = lane >> 2;
    int lc8 = (lane & 3) * 8;
    int gc8 = (((lane & 3) - (rsub >> 1)) & 3) * 8;
    int pf8 = ((quad + (l15 >> 1)) & 3) * 8;

    f32x4 acc[4][4];
    #pragma unroll
    for (int i = 0; i < 4; ++i)
        #pragma unroll
        for (int j = 0; j < 4; ++j) acc[i][j] = (f32x4){0.f, 0.f, 0.f, 0.f};

    for (int kt = 0; kt < K; kt += BK) {
        #pragma unroll
        for (int i = 0; i < 2; ++i) {
            int r = i * 64 + wv * 16 + rsub;
            gload16(Ah + (size_t)(bm + r) * K + kt + gc8, &Ash[r * BK + lc8]);
            gload16(Bh + (size_t)(bn + r) * K + kt + gc8, &Bsh[r * BK + lc8]);
        }
        __syncthreads();
        bf16x8 fah[4], fbh[4];
        #pragma unroll
        for (int i = 0; i < 4; ++i)
            fah[i] = *(const bf16x8*)&Ash[(wr * 64 + i * 16 + l15) * BK + pf8];
        #pragma unroll
        for (int j = 0; j < 4; ++j)
            fbh[j] = *(const bf16x8*)&Bsh[(wc * 64 + j * 16 + l15) * BK + pf8];
        #pragma unroll
        for (int i = 0; i < 4; ++i)
            #pragma unroll
            for (int j = 0; j < 4; ++j)
                acc[i][j] = MFMA16(fah[i], fbh[j], acc[i][j]);
        __syncthreads();
    }

    float alpha = alphap[0];
    float scale = powf(sqrtf((float)N3C) / logf(1.0f + (float)N3C), alpha);
    int segc0 = bn + wc * 64;          // wave-uniform
    int seg = segc0 >> 10;             // 0=Q 1=K 2=V
    int h = (segc0 >> 6) & 15;
    int bglob = bm >> 11;
    int bh = bglob * NH + h;

    if (seg < 2) {
        u16* dst = (seg == 0) ? Qb : Kb;
        float qs = (seg == 0) ? 0.125f : 1.0f;
        #pragma unroll
        for (int i = 0; i < 4; ++i) {
            int tb = bm + wr * 64 + i * 16 + quad * 4;
            #pragma unroll
            for (int r = 0; r < 4; ++r) {
                int row = tb + r;
                int t = row & (TSEQ - 1);
                float rs = rowsq[row];
                float y[4];
                #pragma unroll
                for (int j = 0; j < 4; ++j) {
                    int col = segc0 + j * 16 + l15;
                    float dot = acc[i][j][r];
                    float dist = rs + colsq[col] - 2.0f * dot + EPSY;
                    y[j] = dot * dot / dist * scale + bias[col];
                }
                float2 sc0 = ropeSC[t * 32 + l15];
                float2 sc1 = ropeSC[t * 32 + 16 + l15];
                float c0 = sc0.x, s0 = sc0.y, c1 = sc1.x, s1 = sc1.y;
                size_t ob = ((size_t)bh * TSEQ + t) * HD;
                dst[ob + l15]      = f2bf((y[0] * c0 - y[2] * s0) * qs);
                dst[ob + 16 + l15] = f2bf((y[1] * c1 - y[3] * s1) * qs);
                dst[ob + 32 + l15] = f2bf((y[2] * c0 + y[0] * s0) * qs);
                dst[ob + 48 + l15] = f2bf((y[3] * c1 + y[1] * s1) * qs);
            }
        }
    } else {
        #pragma unroll
        for (int i = 0; i < 4; ++i) {
            int tb = bm + wr * 64 + i * 16 + quad * 4;
            int t0 = tb & (TSEQ - 1);
            #pragma unroll
            for (int j = 0; j < 4; ++j) {
                int col = segc0 + j * 16 + l15;
                int d = j * 16 + l15;
                float cs = colsq[col], bi = bias[col];
                ushort4 pk;
                u16* pp = (u16*)&pk;
                #pragma unroll
                for (int r = 0; r < 4; ++r) {
                    float dot = acc[i][j][r];
                    float dist = rowsq[tb + r] + cs - 2.0f * dot + EPSY;
                    pp[r] = f2bf(dot * dot / dist * scale + bi);
                }
                *(ushort4*)(Vt + ((size_t)bh * HD + d) * TSEQ + t0) = pk;
            }
        }
    }
}

// ---------------------------------------------------------------------------
// GEMM2: single-bf16 MFMA + yat epilogue, fp32 out. Error analysis (R7/R8):
// dropped lo-product terms contribute ~4e-6 to output vs 3.05e-5 floor set
// by the attention path. 128x64 tile, swizzled LDS.
__global__ __launch_bounds__(256, 4) void gemm_yat_mfma(
    const u16* __restrict__ Ah, const u16* __restrict__ Bh,
    const float* __restrict__ bias, const float* __restrict__ rowsq,
    const float* __restrict__ colsq, const float* __restrict__ alphap,
    float* __restrict__ outp, int M, int N, int K, float outf) {
    constexpr int BM = 128, BN = 64, BK = 32;
    __shared__ u16 Ash[BM * BK], Bsh[BN * BK];
    int tid = threadIdx.x;
    int lane = tid & 63, wv = tid >> 6;
    int quad = lane >> 4, l15 = lane & 15;
    int bm = blockIdx.y * BM, bn = blockIdx.x * BN;
    int rsub = lane >> 2;
    int lc8 = (lane & 3) * 8;
    int gc8 = (((lane & 3) - (rsub >> 1)) & 3) * 8;
    int pf8 = ((quad + (l15 >> 1)) & 3) * 8;

    f32x4 acc[2][4];
    #pragma unroll
    for (int i = 0; i < 2; ++i)
        #pragma unroll
        for (int j = 0; j < 4; ++j) acc[i][j] = (f32x4){0.f, 0.f, 0.f, 0.f};

    for (int kt = 0; kt < K; kt += BK) {
        #pragma unroll
        for (int i = 0; i < 2; ++i) {
            int r = i * 64 + wv * 16 + rsub;
            gload16(Ah + (size_t)(bm + r) * K + kt + gc8, &Ash[r * BK + lc8]);
        }
        {
            int r = wv * 16 + rsub;
            gload16(Bh + (size_t)(bn + r) * K + kt + gc8, &Bsh[r * BK + lc8]);
        }
        __syncthreads();
        bf16x8 fah[2], fbh[4];
        #pragma unroll
        for (int i = 0; i < 2; ++i)
            fah[i] = *(const bf16x8*)&Ash[(wv * 32 + i * 16 + l15) * BK + pf8];
        #pragma unroll
        for (int j = 0; j < 4; ++j)
            fbh[j] = *(const bf16x8*)&Bsh[(j * 16 + l15) * BK + pf8];
        #pragma unroll
        for (int i = 0; i < 2; ++i)
            #pragma unroll
            for (int j = 0; j < 4; ++j)
                acc[i][j] = MFMA16(fah[i], fbh[j], acc[i][j]);
        __syncthreads();
    }

    float alpha = alphap[0];
    float scale = powf(sqrtf(outf) / logf(1.0f + outf), alpha);
    #pragma unroll
    for (int j = 0; j < 4; ++j) {
        int col = bn + j * 16 + l15;
        float cs = colsq[col], bi = bias[col];
        #pragma unroll
        for (int i = 0; i < 2; ++i) {
            #pragma unroll
            for (int r = 0; r < 4; ++r) {
                int row = bm + wv * 32 + i * 16 + quad * 4 + r;
                float dot = acc[i][j][r];
                float dist = rowsq[row] + cs - 2.0f * dot + EPSY;
                outp[(size_t)row * N + col] = dot * dot / dist * scale + bi;
            }
        }
    }
}

// ---------------------------------------------------------------------------
// S^T-formulation bf16 MFMA causal flash attention, FIXED-SHIFT softmax:
// scores are bounded (|S| <= ~0.5: yat outputs are small; Q pre-scaled
// 1/8), so softmax uses shift c=0 — no online max, no o-rescale, and the
// cross-quad l-reduction is deferred to after the k-loop.
// 64-key tiles, grid (16, B*H), paired passes (qb, 31-qb).
__global__ __launch_bounds__(256) void attn_mfma(
    const u16* __restrict__ Qb, const u16* __restrict__ Kb,
    const u16* __restrict__ Vt, float* __restrict__ ctx) {
    __shared__ u16 Ksh[64 * 64];   // [key][d-chunks, rotated by key]
    __shared__ u16 Vsh[64 * 64];   // [d][key-chunks, rotated by d]
    int tid = threadIdx.x;
    int lane = tid & 63, wv = tid >> 6;
    int quad = lane >> 4, l15 = lane & 15;
    int bh = blockIdx.y;
    int b = bh >> 4, h = bh & 15;
    const u16* Qh = Qb + (size_t)bh * TSEQ * HD;
    const u16* Kh = Kb + (size_t)bh * TSEQ * HD;
    const u16* Vh = Vt + (size_t)bh * HD * TSEQ;
    const f32x4 zf = {0.f, 0.f, 0.f, 0.f};

    for (int pass = 0; pass < 2; ++pass) {
        int qb = pass ? (31 - blockIdx.x) : blockIdx.x;
        int qw = qb * 64 + wv * 16;
        bf16x8 bq0 = *(const bf16x8*)(Qh + (size_t)(qw + l15) * HD + quad * 8);
        bf16x8 bq1 = *(const bf16x8*)(Qh + (size_t)(qw + l15) * HD + 32 + quad * 8);

        f32x4 o[4] = {zf, zf, zf, zf};
        float l = 0.f;

        for (int kt = 0; kt <= qb; ++kt) {
            int k0 = kt * 64;
            __syncthreads();
            #pragma unroll
            for (int p = 0; p < 2; ++p) {
                int lin = p * 256 + tid;
                int rowi = lin >> 3, ch = lin & 7;
                int gk = (ch + rowi) & 7;
                gload16(Kh + (size_t)(k0 + rowi) * HD + gk * 8, &Ksh[lin * 8]);
                gload16(Vh + (size_t)rowi * TSEQ + k0 + gk * 8, &Vsh[lin * 8]);
            }
            __syncthreads();

            f32x4 st[4];
            #pragma unroll
            for (int mt = 0; mt < 4; ++mt) {
                int key = mt * 16 + l15;
                bf16x8 a0 = *(const bf16x8*)&Ksh[key * 64 + ((quad - key) & 7) * 8];
                bf16x8 a1 = *(const bf16x8*)&Ksh[key * 64 + ((4 + quad - key) & 7) * 8];
                st[mt] = MFMA16(a0, bq0, zf);
                st[mt] = MFMA16(a1, bq1, st[mt]);
            }
            if (kt == qb) {
                int q = qw + l15;
                #pragma unroll
                for (int mt = 0; mt < 4; ++mt)
                    #pragma unroll
                    for (int r = 0; r < 4; ++r)
                        if (k0 + mt * 16 + quad * 4 + r > q) st[mt][r] = -1e30f;
            }
            u32 pp[4][2];
            #pragma unroll
            for (int mt = 0; mt < 4; ++mt) {
                float p0 = __expf(st[mt][0]);
                float p1 = __expf(st[mt][1]);
                float p2 = __expf(st[mt][2]);
                float p3 = __expf(st[mt][3]);
                l += (p0 + p1) + (p2 + p3);
                pp[mt][0] = (u32)f2bf(p0) | ((u32)f2bf(p1) << 16);
                pp[mt][1] = (u32)f2bf(p2) | ((u32)f2bf(p3) << 16);
            }
            // PV: shuffle BOTH mt-candidates, select on the DESTINATION side.
            #pragma unroll
            for (int s = 0; s < 2; ++s) {
                u32 bw[4];
                #pragma unroll
                for (int w = 0; w < 4; ++w) {
                    int srcl = (((quad & 1) * 2 + (w >> 1)) << 4) + l15;
                    u32 vlo = (u32)__shfl((int)pp[2 * s][w & 1], srcl, 64);
                    u32 vhi = (u32)__shfl((int)pp[2 * s + 1][w & 1], srcl, 64);
                    bw[w] = (quad & 2) ? vhi : vlo;
                }
                bf16x8 bfr;
                *(u32*)&((short*)&bfr)[0] = bw[0];
                *(u32*)&((short*)&bfr)[2] = bw[1];
                *(u32*)&((short*)&bfr)[4] = bw[2];
                *(u32*)&((short*)&bfr)[6] = bw[3];
                #pragma unroll
                for (int dt = 0; dt < 4; ++dt) {
                    int d = dt * 16 + l15;
                    bf16x8 av = *(const bf16x8*)&Vsh[d * 64 + ((s * 4 + quad - d) & 7) * 8];
                    o[dt] = MFMA16(av, bfr, o[dt]);
                }
            }
        }

        // deferred cross-quad l reduction (sum over all 64 keys' lanes)
        l += __shfl_xor(l, 16, 64);
        l += __shfl_xor(l, 32, 64);
        float inv = 1.0f / l;
        #pragma unroll
        for (int dt = 0; dt < 4; ++dt) {
            float4 r;
            r.x = o[dt][0] * inv; r.y = o[dt][1] * inv;
            r.z = o[dt][2] * inv; r.w = o[dt][3] * inv;
            *(float4*)(ctx + ((size_t)b * TSEQ + qw + l15) * CDIM
                       + h * HD + dt * 16 + quad * 4) = r;
        }
    }
}

// ---------------------------------------------------------------------------
extern "C" void kernel_launch(void* const* d_in, const int* in_sizes, int n_in,
                              void* d_out, int out_size, void* d_ws, size_t ws_size,
                              hipStream_t stream) {
    const float* x      = (const float*)d_in[0];
    const float* w_attn = (const float*)d_in[2];
    const float* b_attn = (const float*)d_in[3];
    const float* a_attn = (const float*)d_in[4];
    const float* w_proj = (const float*)d_in[5];
    const float* b_proj = (const float*)d_in[6];
    const float* a_proj = (const float*)d_in[7];
    float* outp = (float*)d_out;

    char* ws = (char*)d_ws;
    float* ksq = (float*)(ws);
    float* xsq = (float*)(ws + 16384);
    float* osq = (float*)(ws + 32768);
    char* pA  = ws + 65536;                    // 16.78 MB: Ahi -> ctx
    u16* Ahi = (u16*)pA;
    float* ctx = (float*)pA;                   // alias (A dead after GEMM1)
    char* pWt = pA + 16777216;                 // 6.29 MB
    u16* Wthi = (u16*)pWt;
    char* pWp = pWt + 6291456;                 // 2.10 MB
    u16* Wphi = (u16*)pWp;
    char* pQ = pWp + 2097152;                  // 25.17 MB: Qb,Kb,Vt
    u16* Qb = (u16*)pQ;
    u16* Kb = (u16*)(pQ + 8388608);
    u16* Vt = (u16*)(pQ + 16777216);
    u16* Chi = (u16*)pQ;                       // alias (Q/K dead after attn)
    float2* ropeSC = (float2*)(pQ + 25165824); // 512 KB

    rope_init<<<256, 256, 0, stream>>>(ropeSC);
    colsq_kernel<<<64, 256, 0, stream>>>(w_attn, w_proj, ksq);
    convert_rows<<<BATCH * TSEQ, 256, 0, stream>>>(x, Ahi, xsq);
    convert_wT<<<dim3(N3C / 64, CDIM / 64), 256, 0, stream>>>(w_attn, Wthi, CDIM, N3C);
    convert_wT<<<dim3(CDIM / 64, CDIM / 64), 256, 0, stream>>>(w_proj, Wphi, CDIM, CDIM);
    gemm1_fused<<<dim3(N3C / 128, (BATCH * TSEQ) / 128), 256, 0, stream>>>(
        Ahi, Wthi, b_attn, xsq, ksq, a_attn, ropeSC, Qb, Kb, Vt);
    attn_mfma<<<dim3(16, BATCH * NH), 256, 0, stream>>>(Qb, Kb, Vt, ctx);
    convert_rows<<<BATCH * TSEQ, 256, 0, stream>>>(ctx, Chi, osq);
    gemm_yat_mfma<<<dim3(CDIM / 64, (BATCH * TSEQ) / 128), 256, 0, stream>>>(
        Chi, Wphi, b_proj, osq, ksq + N3C, a_proj, outp,
        BATCH * TSEQ, CDIM, CDIM, (float)CDIM);
}

// Round 9
// 248.841 us; speedup vs baseline: 1.6843x; 1.0850x over previous
//
#include <hip/hip_runtime.h>
#include <math.h>

#define TSEQ  2048
#define BATCH 2
#define NH    16
#define HD    64
#define CDIM  1024
#define N3C   3072
#define EPSY  1e-6f

typedef unsigned short u16;
typedef unsigned int u32;
typedef __attribute__((ext_vector_type(8))) short bf16x8;
typedef __attribute__((ext_vector_type(4))) float f32x4;

#define MFMA16(a, b, c) __builtin_amdgcn_mfma_f32_16x16x32_bf16(a, b, c, 0, 0, 0)

__device__ __forceinline__ u16 f2bf(float f) {
    unsigned u = __float_as_uint(f);
    return (u16)((u + 0x7fffu + ((u >> 16) & 1u)) >> 16);
}
__device__ __forceinline__ float bf2f(u16 h) {
    return __uint_as_float(((unsigned)h) << 16);
}
__device__ __forceinline__ void gload16(const void* g, void* l) {
    __builtin_amdgcn_global_load_lds(
        (const __attribute__((address_space(1))) unsigned int*)g,
        (__attribute__((address_space(3))) unsigned int*)l, 16, 0, 0);
}

// ---------------------------------------------------------------------------
// rope table + osq zero-init (osq accumulated by attn via atomics).
__global__ void rope_init(float2* __restrict__ sc, float* __restrict__ osq) {
    int idx = blockIdx.x * 256 + threadIdx.x;   // 2048*32
    if (idx < BATCH * TSEQ) osq[idx] = 0.f;
    int t = idx >> 5, j = idx & 31;
    float inv = exp2f(-(float)j * 0.4152410118609203f);  // 10000^(-2j/64)
    float ang = (float)t * inv;
    sc[idx] = make_float2(cosf(ang), sinf(ang));
}

// ---------------------------------------------------------------------------
__global__ void colsq_kernel(const float* __restrict__ wa,
                             const float* __restrict__ wp,
                             float* __restrict__ ks) {
    int bid = blockIdx.x, tid = threadIdx.x;
    int c = tid & 63, kq = tid >> 6;
    const float* W; int N, col, outoff;
    if (bid < 48) { W = wa; N = N3C;  col = bid * 64 + c;        outoff = 0;   }
    else          { W = wp; N = CDIM; col = (bid - 48) * 64 + c; outoff = N3C; }
    float s = 0.f;
    int i0 = kq * 256;
    #pragma unroll 4
    for (int i = i0; i < i0 + 256; ++i) {
        float v = W[(size_t)i * N + col];
        s = fmaf(v, v, s);
    }
    __shared__ float red[256];
    red[tid] = s;
    __syncthreads();
    if (kq == 0) ks[outoff + col] = red[c] + red[64 + c] + red[128 + c] + red[192 + c];
}

// ---------------------------------------------------------------------------
__global__ void convert_rows(const float* __restrict__ X, u16* __restrict__ Xhi,
                             float* __restrict__ rsq) {
    int row = blockIdx.x, tid = threadIdx.x;
    int lane = tid & 63, wv = tid >> 6;
    size_t base = (size_t)row * CDIM + tid * 4;
    float4 v = *(const float4*)(X + base);
    ushort4 hi;
    hi.x = f2bf(v.x); hi.y = f2bf(v.y); hi.z = f2bf(v.z); hi.w = f2bf(v.w);
    *(ushort4*)(Xhi + base) = hi;
    float s = v.x * v.x + v.y * v.y + v.z * v.z + v.w * v.w;
    #pragma unroll
    for (int off = 32; off; off >>= 1) s += __shfl_down(s, off, 64);
    __shared__ float red[4];
    if (lane == 0) red[wv] = s;
    __syncthreads();
    if (tid == 0) rsq[row] = red[0] + red[1] + red[2] + red[3];
}

// ---------------------------------------------------------------------------
__global__ void convert_wT(const float* __restrict__ W, u16* __restrict__ Whi,
                           int K, int N) {
    __shared__ float tile[64][68];
    int k0 = blockIdx.y * 64, n0 = blockIdx.x * 64;
    int tid = threadIdx.x;
    int r = tid >> 4, c4 = (tid & 15) * 4;
    #pragma unroll
    for (int i = 0; i < 4; ++i) {
        int k = k0 + r + i * 16;
        float4 v = *(const float4*)(W + (size_t)k * N + n0 + c4);
        *(float4*)&tile[r + i * 16][c4] = v;
    }
    __syncthreads();
    int n = tid >> 4, k4 = (tid & 15) * 4;
    #pragma unroll
    for (int i = 0; i < 4; ++i) {
        int nn = n + i * 16;
        ushort4 hi;
        hi.x = f2bf(tile[k4 + 0][nn]);
        hi.y = f2bf(tile[k4 + 1][nn]);
        hi.z = f2bf(tile[k4 + 2][nn]);
        hi.w = f2bf(tile[k4 + 3][nn]);
        *(ushort4*)(Whi + (size_t)(n0 + nn) * K + k0 + k4) = hi;
    }
}

// ---------------------------------------------------------------------------
// GEMM1: single-bf16 MFMA, yat epilogue + rotary table + bf16 pack.
// XOR-swizzled LDS staging (0 bank conflicts). 4 blocks/CU pinned.
__global__ __launch_bounds__(256, 4) void gemm1_fused(
    const u16* __restrict__ Ah, const u16* __restrict__ Bh,
    const float* __restrict__ bias, const float* __restrict__ rowsq,
    const float* __restrict__ colsq, const float* __restrict__ alphap,
    const float2* __restrict__ ropeSC,
    u16* __restrict__ Qb, u16* __restrict__ Kb, u16* __restrict__ Vt) {
    constexpr int BK = 32;
    const int K = CDIM;
    __shared__ u16 Ash[128 * BK], Bsh[128 * BK];
    int tid = threadIdx.x;
    int lane = tid & 63, wv = tid >> 6;
    int quad = lane >> 4, l15 = lane & 15;
    int wr = wv >> 1, wc = wv & 1;
    int bm = blockIdx.y * 128, bn = blockIdx.x * 128;
    int rsub = lane >> 2;
    int lc8 = (lane & 3) * 8;
    int gc8 = (((lane & 3) - (rsub >> 1)) & 3) * 8;
    int pf8 = ((quad + (l15 >> 1)) & 3) * 8;

    f32x4 acc[4][4];
    #pragma unroll
    for (int i = 0; i < 4; ++i)
        #pragma unroll
        for (int j = 0; j < 4; ++j) acc[i][j] = (f32x4){0.f, 0.f, 0.f, 0.f};

    for (int kt = 0; kt < K; kt += BK) {
        #pragma unroll
        for (int i = 0; i < 2; ++i) {
            int r = i * 64 + wv * 16 + rsub;
            gload16(Ah + (size_t)(bm + r) * K + kt + gc8, &Ash[r * BK + lc8]);
            gload16(Bh + (size_t)(bn + r) * K + kt + gc8, &Bsh[r * BK + lc8]);
        }
        __syncthreads();
        bf16x8 fah[4], fbh[4];
        #pragma unroll
        for (int i = 0; i < 4; ++i)
            fah[i] = *(const bf16x8*)&Ash[(wr * 64 + i * 16 + l15) * BK + pf8];
        #pragma unroll
        for (int j = 0; j < 4; ++j)
            fbh[j] = *(const bf16x8*)&Bsh[(wc * 64 + j * 16 + l15) * BK + pf8];
        #pragma unroll
        for (int i = 0; i < 4; ++i)
            #pragma unroll
            for (int j = 0; j < 4; ++j)
                acc[i][j] = MFMA16(fah[i], fbh[j], acc[i][j]);
        __syncthreads();
    }

    float alpha = alphap[0];
    float scale = powf(sqrtf((float)N3C) / logf(1.0f + (float)N3C), alpha);
    int segc0 = bn + wc * 64;          // wave-uniform
    int seg = segc0 >> 10;             // 0=Q 1=K 2=V
    int h = (segc0 >> 6) & 15;
    int bglob = bm >> 11;
    int bh = bglob * NH + h;

    if (seg < 2) {
        u16* dst = (seg == 0) ? Qb : Kb;
        float qs = (seg == 0) ? 0.125f : 1.0f;
        #pragma unroll
        for (int i = 0; i < 4; ++i) {
            int tb = bm + wr * 64 + i * 16 + quad * 4;
            #pragma unroll
            for (int r = 0; r < 4; ++r) {
                int row = tb + r;
                int t = row & (TSEQ - 1);
                float rs = rowsq[row];
                float y[4];
                #pragma unroll
                for (int j = 0; j < 4; ++j) {
                    int col = segc0 + j * 16 + l15;
                    float dot = acc[i][j][r];
                    float dist = rs + colsq[col] - 2.0f * dot + EPSY;
                    y[j] = dot * dot / dist * scale + bias[col];
                }
                float2 sc0 = ropeSC[t * 32 + l15];
                float2 sc1 = ropeSC[t * 32 + 16 + l15];
                float c0 = sc0.x, s0 = sc0.y, c1 = sc1.x, s1 = sc1.y;
                size_t ob = ((size_t)bh * TSEQ + t) * HD;
                dst[ob + l15]      = f2bf((y[0] * c0 - y[2] * s0) * qs);
                dst[ob + 16 + l15] = f2bf((y[1] * c1 - y[3] * s1) * qs);
                dst[ob + 32 + l15] = f2bf((y[2] * c0 + y[0] * s0) * qs);
                dst[ob + 48 + l15] = f2bf((y[3] * c1 + y[1] * s1) * qs);
            }
        }
    } else {
        #pragma unroll
        for (int i = 0; i < 4; ++i) {
            int tb = bm + wr * 64 + i * 16 + quad * 4;
            int t0 = tb & (TSEQ - 1);
            #pragma unroll
            for (int j = 0; j < 4; ++j) {
                int col = segc0 + j * 16 + l15;
                int d = j * 16 + l15;
                float cs = colsq[col], bi = bias[col];
                ushort4 pk;
                u16* pp = (u16*)&pk;
                #pragma unroll
                for (int r = 0; r < 4; ++r) {
                    float dot = acc[i][j][r];
                    float dist = rowsq[tb + r] + cs - 2.0f * dot + EPSY;
                    pp[r] = f2bf(dot * dot / dist * scale + bi);
                }
                *(ushort4*)(Vt + ((size_t)bh * HD + d) * TSEQ + t0) = pk;
            }
        }
    }
}

// ---------------------------------------------------------------------------
// GEMM2: single-bf16 MFMA + yat epilogue, fp32 out. 128x64 tile, swizzled.
__global__ __launch_bounds__(256, 4) void gemm_yat_mfma(
    const u16* __restrict__ Ah, const u16* __restrict__ Bh,
    const float* __restrict__ bias, const float* __restrict__ rowsq,
    const float* __restrict__ colsq, const float* __restrict__ alphap,
    float* __restrict__ outp, int M, int N, int K, float outf) {
    constexpr int BM = 128, BN = 64, BK = 32;
    __shared__ u16 Ash[BM * BK], Bsh[BN * BK];
    int tid = threadIdx.x;
    int lane = tid & 63, wv = tid >> 6;
    int quad = lane >> 4, l15 = lane & 15;
    int bm = blockIdx.y * BM, bn = blockIdx.x * BN;
    int rsub = lane >> 2;
    int lc8 = (lane & 3) * 8;
    int gc8 = (((lane & 3) - (rsub >> 1)) & 3) * 8;
    int pf8 = ((quad + (l15 >> 1)) & 3) * 8;

    f32x4 acc[2][4];
    #pragma unroll
    for (int i = 0; i < 2; ++i)
        #pragma unroll
        for (int j = 0; j < 4; ++j) acc[i][j] = (f32x4){0.f, 0.f, 0.f, 0.f};

    for (int kt = 0; kt < K; kt += BK) {
        #pragma unroll
        for (int i = 0; i < 2; ++i) {
            int r = i * 64 + wv * 16 + rsub;
            gload16(Ah + (size_t)(bm + r) * K + kt + gc8, &Ash[r * BK + lc8]);
        }
        {
            int r = wv * 16 + rsub;
            gload16(Bh + (size_t)(bn + r) * K + kt + gc8, &Bsh[r * BK + lc8]);
        }
        __syncthreads();
        bf16x8 fah[2], fbh[4];
        #pragma unroll
        for (int i = 0; i < 2; ++i)
            fah[i] = *(const bf16x8*)&Ash[(wv * 32 + i * 16 + l15) * BK + pf8];
        #pragma unroll
        for (int j = 0; j < 4; ++j)
            fbh[j] = *(const bf16x8*)&Bsh[(j * 16 + l15) * BK + pf8];
        #pragma unroll
        for (int i = 0; i < 2; ++i)
            #pragma unroll
            for (int j = 0; j < 4; ++j)
                acc[i][j] = MFMA16(fah[i], fbh[j], acc[i][j]);
        __syncthreads();
    }

    float alpha = alphap[0];
    float scale = powf(sqrtf(outf) / logf(1.0f + outf), alpha);
    #pragma unroll
    for (int j = 0; j < 4; ++j) {
        int col = bn + j * 16 + l15;
        float cs = colsq[col], bi = bias[col];
        #pragma unroll
        for (int i = 0; i < 2; ++i) {
            #pragma unroll
            for (int r = 0; r < 4; ++r) {
                int row = bm + wv * 32 + i * 16 + quad * 4 + r;
                float dot = acc[i][j][r];
                float dist = rowsq[row] + cs - 2.0f * dot + EPSY;
                outp[(size_t)row * N + col] = dot * dot / dist * scale + bi;
            }
        }
    }
}

// ---------------------------------------------------------------------------
// S^T bf16 MFMA causal flash attention, fixed-shift softmax.
// grid (bh=32, qbRank=32): one qb per block, descending (LPT); blockIdx.x=bh
// keeps all qb-blocks of a bh on one XCD (linear%8 = bh%8) for L2 reuse of
// that bh's 0.5 MB K/V. Epilogue writes bf16 Chi directly + atomic osq
// (fuses the old convert_rows(ctx) pass).
__global__ __launch_bounds__(256) void attn_mfma(
    const u16* __restrict__ Qb, const u16* __restrict__ Kb,
    const u16* __restrict__ Vt, u16* __restrict__ Chi,
    float* __restrict__ osq) {
    __shared__ u16 Ksh[64 * 64];   // [key][d-chunks, rotated by key]
    __shared__ u16 Vsh[64 * 64];   // [d][key-chunks, rotated by d]
    int tid = threadIdx.x;
    int lane = tid & 63, wv = tid >> 6;
    int quad = lane >> 4, l15 = lane & 15;
    int bh = blockIdx.x;
    int b = bh >> 4, h = bh & 15;
    const u16* Qh = Qb + (size_t)bh * TSEQ * HD;
    const u16* Kh = Kb + (size_t)bh * TSEQ * HD;
    const u16* Vh = Vt + (size_t)bh * HD * TSEQ;
    const f32x4 zf = {0.f, 0.f, 0.f, 0.f};

    int qb = 31 - blockIdx.y;
    int qw = qb * 64 + wv * 16;
    bf16x8 bq0 = *(const bf16x8*)(Qh + (size_t)(qw + l15) * HD + quad * 8);
    bf16x8 bq1 = *(const bf16x8*)(Qh + (size_t)(qw + l15) * HD + 32 + quad * 8);

    f32x4 o[4] = {zf, zf, zf, zf};
    float l = 0.f;

    for (int kt = 0; kt <= qb; ++kt) {
        int k0 = kt * 64;
        __syncthreads();
        #pragma unroll
        for (int p = 0; p < 2; ++p) {
            int lin = p * 256 + tid;
            int rowi = lin >> 3, ch = lin & 7;
            int gk = (ch + rowi) & 7;
            gload16(Kh + (size_t)(k0 + rowi) * HD + gk * 8, &Ksh[lin * 8]);
            gload16(Vh + (size_t)rowi * TSEQ + k0 + gk * 8, &Vsh[lin * 8]);
        }
        __syncthreads();

        f32x4 st[4];
        #pragma unroll
        for (int mt = 0; mt < 4; ++mt) {
            int key = mt * 16 + l15;
            bf16x8 a0 = *(const bf16x8*)&Ksh[key * 64 + ((quad - key) & 7) * 8];
            bf16x8 a1 = *(const bf16x8*)&Ksh[key * 64 + ((4 + quad - key) & 7) * 8];
            st[mt] = MFMA16(a0, bq0, zf);
            st[mt] = MFMA16(a1, bq1, st[mt]);
        }
        if (kt == qb) {
            int q = qw + l15;
            #pragma unroll
            for (int mt = 0; mt < 4; ++mt)
                #pragma unroll
                for (int r = 0; r < 4; ++r)
                    if (k0 + mt * 16 + quad * 4 + r > q) st[mt][r] = -1e30f;
        }
        u32 pp[4][2];
        #pragma unroll
        for (int mt = 0; mt < 4; ++mt) {
            float p0 = __expf(st[mt][0]);
            float p1 = __expf(st[mt][1]);
            float p2 = __expf(st[mt][2]);
            float p3 = __expf(st[mt][3]);
            l += (p0 + p1) + (p2 + p3);
            pp[mt][0] = (u32)f2bf(p0) | ((u32)f2bf(p1) << 16);
            pp[mt][1] = (u32)f2bf(p2) | ((u32)f2bf(p3) << 16);
        }
        // PV: shuffle BOTH mt-candidates, select on the DESTINATION side.
        #pragma unroll
        for (int s = 0; s < 2; ++s) {
            u32 bw[4];
            #pragma unroll
            for (int w = 0; w < 4; ++w) {
                int srcl = (((quad & 1) * 2 + (w >> 1)) << 4) + l15;
                u32 vlo = (u32)__shfl((int)pp[2 * s][w & 1], srcl, 64);
                u32 vhi = (u32)__shfl((int)pp[2 * s + 1][w & 1], srcl, 64);
                bw[w] = (quad & 2) ? vhi : vlo;
            }
            bf16x8 bfr;
            *(u32*)&((short*)&bfr)[0] = bw[0];
            *(u32*)&((short*)&bfr)[2] = bw[1];
            *(u32*)&((short*)&bfr)[4] = bw[2];
            *(u32*)&((short*)&bfr)[6] = bw[3];
            #pragma unroll
            for (int dt = 0; dt < 4; ++dt) {
                int d = dt * 16 + l15;
                bf16x8 av = *(const bf16x8*)&Vsh[d * 64 + ((s * 4 + quad - d) & 7) * 8];
                o[dt] = MFMA16(av, bfr, o[dt]);
            }
        }
    }

    // deferred cross-quad l reduction, bf16 write, fused row-sumsq
    l += __shfl_xor(l, 16, 64);
    l += __shfl_xor(l, 32, 64);
    float inv = 1.0f / l;
    int row = (b << 11) + qw + l15;
    float ss = 0.f;
    #pragma unroll
    for (int dt = 0; dt < 4; ++dt) {
        float v0 = o[dt][0] * inv, v1 = o[dt][1] * inv;
        float v2 = o[dt][2] * inv, v3 = o[dt][3] * inv;
        ss += v0 * v0 + v1 * v1 + v2 * v2 + v3 * v3;
        ushort4 pk;
        pk.x = f2bf(v0); pk.y = f2bf(v1); pk.z = f2bf(v2); pk.w = f2bf(v3);
        *(ushort4*)(Chi + (size_t)row * CDIM + h * HD + dt * 16 + quad * 4) = pk;
    }
    ss += __shfl_xor(ss, 16, 64);
    ss += __shfl_xor(ss, 32, 64);
    if (quad == 0) atomicAdd(osq + row, ss);
}

// ---------------------------------------------------------------------------
extern "C" void kernel_launch(void* const* d_in, const int* in_sizes, int n_in,
                              void* d_out, int out_size, void* d_ws, size_t ws_size,
                              hipStream_t stream) {
    const float* x      = (const float*)d_in[0];
    const float* w_attn = (const float*)d_in[2];
    const float* b_attn = (const float*)d_in[3];
    const float* a_attn = (const float*)d_in[4];
    const float* w_proj = (const float*)d_in[5];
    const float* b_proj = (const float*)d_in[6];
    const float* a_proj = (const float*)d_in[7];
    float* outp = (float*)d_out;

    char* ws = (char*)d_ws;
    float* ksq = (float*)(ws);
    float* xsq = (float*)(ws + 16384);
    float* osq = (float*)(ws + 32768);
    char* pA  = ws + 65536;                    // 16.78 MB: Ahi -> Chi
    u16* Ahi = (u16*)pA;
    u16* Chi = (u16*)pA;                       // alias (Ahi dead after GEMM1)
    char* pWt = pA + 16777216;                 // 6.29 MB
    u16* Wthi = (u16*)pWt;
    char* pWp = pWt + 6291456;                 // 2.10 MB
    u16* Wphi = (u16*)pWp;
    char* pQ = pWp + 2097152;                  // 25.17 MB: Qb,Kb,Vt
    u16* Qb = (u16*)pQ;
    u16* Kb = (u16*)(pQ + 8388608);
    u16* Vt = (u16*)(pQ + 16777216);
    float2* ropeSC = (float2*)(pQ + 25165824); // 512 KB

    rope_init<<<256, 256, 0, stream>>>(ropeSC, osq);
    colsq_kernel<<<64, 256, 0, stream>>>(w_attn, w_proj, ksq);
    convert_rows<<<BATCH * TSEQ, 256, 0, stream>>>(x, Ahi, xsq);
    convert_wT<<<dim3(N3C / 64, CDIM / 64), 256, 0, stream>>>(w_attn, Wthi, CDIM, N3C);
    convert_wT<<<dim3(CDIM / 64, CDIM / 64), 256, 0, stream>>>(w_proj, Wphi, CDIM, CDIM);
    gemm1_fused<<<dim3(N3C / 128, (BATCH * TSEQ) / 128), 256, 0, stream>>>(
        Ahi, Wthi, b_attn, xsq, ksq, a_attn, ropeSC, Qb, Kb, Vt);
    attn_mfma<<<dim3(BATCH * NH, 32), 256, 0, stream>>>(Qb, Kb, Vt, Chi, osq);
    gemm_yat_mfma<<<dim3(CDIM / 64, (BATCH * TSEQ) / 128), 256, 0, stream>>>(
        Chi, Wphi, b_proj, osq, ksq + N3C, a_proj, outp,
        BATCH * TSEQ, CDIM, CDIM, (float)CDIM);
}

// Round 10
// 241.075 us; speedup vs baseline: 1.7385x; 1.0322x over previous
//
#include <hip/hip_runtime.h>
#include <math.h>

#define TSEQ  2048
#define BATCH 2
#define NH    16
#define HD    64
#define CDIM  1024
#define N3C   3072
#define EPSY  1e-6f

typedef unsigned short u16;
typedef unsigned int u32;
typedef __attribute__((ext_vector_type(8))) short bf16x8;
typedef __attribute__((ext_vector_type(4))) float f32x4;

#define MFMA16(a, b, c) __builtin_amdgcn_mfma_f32_16x16x32_bf16(a, b, c, 0, 0, 0)

__device__ __forceinline__ u16 f2bf(float f) {
    unsigned u = __float_as_uint(f);
    return (u16)((u + 0x7fffu + ((u >> 16) & 1u)) >> 16);
}
__device__ __forceinline__ float bf2f(u16 h) {
    return __uint_as_float(((unsigned)h) << 16);
}
__device__ __forceinline__ void gload16(const void* g, void* l) {
    __builtin_amdgcn_global_load_lds(
        (const __attribute__((address_space(1))) unsigned int*)g,
        (__attribute__((address_space(3))) unsigned int*)l, 16, 0, 0);
}

// ---------------------------------------------------------------------------
// Fused prep: one launch replaces rope_init/colsq/convert_rows/convert_wT x2.
// Block-role by blockIdx.x range:
//   [0,4096)      convert_rows(x) -> Ahi + xsq
//   [4096,4864)   w_attn^T -> Wthi (48 x 16 tiles)
//   [4864,5120)   w_proj^T -> Wphi (16 x 16 tiles)
//   [5120,5184)   colsq (wa 48 blocks, wp 16 blocks)
//   [5184,5440)   rope table + osq zero
__global__ __launch_bounds__(256) void prep_kernel(
    const float* __restrict__ x, const float* __restrict__ wa,
    const float* __restrict__ wp, u16* __restrict__ Ahi,
    u16* __restrict__ Wthi, u16* __restrict__ Wphi,
    float* __restrict__ ksq, float* __restrict__ xsq,
    float* __restrict__ osq, float2* __restrict__ ropeSC) {
    __shared__ float smem[64 * 68];
    int bid = blockIdx.x, tid = threadIdx.x;

    if (bid < 4096) {                      // ---- convert_rows
        int lane = tid & 63, wv = tid >> 6;
        size_t base = (size_t)bid * CDIM + tid * 4;
        float4 v = *(const float4*)(x + base);
        ushort4 hi;
        hi.x = f2bf(v.x); hi.y = f2bf(v.y); hi.z = f2bf(v.z); hi.w = f2bf(v.w);
        *(ushort4*)(Ahi + base) = hi;
        float s = v.x * v.x + v.y * v.y + v.z * v.z + v.w * v.w;
        #pragma unroll
        for (int off = 32; off; off >>= 1) s += __shfl_down(s, off, 64);
        if (lane == 0) smem[wv] = s;
        __syncthreads();
        if (tid == 0) xsq[bid] = smem[0] + smem[1] + smem[2] + smem[3];
    } else if (bid < 5120) {               // ---- transpose+convert weights
        const float* W; u16* Whi; int K, N, bx, by;
        if (bid < 4864) {
            int t = bid - 4096; W = wa; Whi = Wthi; K = CDIM; N = N3C;
            bx = t % 48; by = t / 48;
        } else {
            int t = bid - 4864; W = wp; Whi = Wphi; K = CDIM; N = CDIM;
            bx = t % 16; by = t / 16;
        }
        int k0 = by * 64, n0 = bx * 64;
        int r = tid >> 4, c4 = (tid & 15) * 4;
        #pragma unroll
        for (int i = 0; i < 4; ++i) {
            int k = k0 + r + i * 16;
            float4 v = *(const float4*)(W + (size_t)k * N + n0 + c4);
            *(float4*)&smem[(r + i * 16) * 68 + c4] = v;
        }
        __syncthreads();
        int n = tid >> 4, k4 = (tid & 15) * 4;
        #pragma unroll
        for (int i = 0; i < 4; ++i) {
            int nn = n + i * 16;
            ushort4 hi;
            hi.x = f2bf(smem[(k4 + 0) * 68 + nn]);
            hi.y = f2bf(smem[(k4 + 1) * 68 + nn]);
            hi.z = f2bf(smem[(k4 + 2) * 68 + nn]);
            hi.w = f2bf(smem[(k4 + 3) * 68 + nn]);
            *(ushort4*)(Whi + (size_t)(n0 + nn) * K + k0 + k4) = hi;
        }
    } else if (bid < 5184) {               // ---- colsq
        int b2 = bid - 5120;
        int c = tid & 63, kq = tid >> 6;
        const float* W; int N, col, outoff;
        if (b2 < 48) { W = wa; N = N3C;  col = b2 * 64 + c;        outoff = 0;   }
        else         { W = wp; N = CDIM; col = (b2 - 48) * 64 + c; outoff = N3C; }
        float s = 0.f;
        int i0 = kq * 256;
        #pragma unroll 4
        for (int i = i0; i < i0 + 256; ++i) {
            float v = W[(size_t)i * N + col];
            s = fmaf(v, v, s);
        }
        smem[tid] = s;
        __syncthreads();
        if (kq == 0)
            ksq[outoff + col] = smem[c] + smem[64 + c] + smem[128 + c] + smem[192 + c];
    } else {                               // ---- rope table + osq zero
        int idx = (bid - 5184) * 256 + tid;   // [0, 65536)
        if (idx < BATCH * TSEQ) osq[idx] = 0.f;
        int t = idx >> 5, j = idx & 31;
        float inv = exp2f(-(float)j * 0.4152410118609203f);
        float ang = (float)t * inv;
        ropeSC[idx] = make_float2(cosf(ang), sinf(ang));
    }
}

// ---------------------------------------------------------------------------
// GEMM1: single-bf16 MFMA, yat epilogue + rotary table + bf16 pack.
// XOR-swizzled LDS staging (0 bank conflicts). 4 blocks/CU pinned.
__global__ __launch_bounds__(256, 4) void gemm1_fused(
    const u16* __restrict__ Ah, const u16* __restrict__ Bh,
    const float* __restrict__ bias, const float* __restrict__ rowsq,
    const float* __restrict__ colsq, const float* __restrict__ alphap,
    const float2* __restrict__ ropeSC,
    u16* __restrict__ Qb, u16* __restrict__ Kb, u16* __restrict__ Vt) {
    constexpr int BK = 32;
    const int K = CDIM;
    __shared__ u16 Ash[128 * BK], Bsh[128 * BK];
    int tid = threadIdx.x;
    int lane = tid & 63, wv = tid >> 6;
    int quad = lane >> 4, l15 = lane & 15;
    int wr = wv >> 1, wc = wv & 1;
    int bm = blockIdx.y * 128, bn = blockIdx.x * 128;
    int rsub = lane >> 2;
    int lc8 = (lane & 3) * 8;
    int gc8 = (((lane & 3) - (rsub >> 1)) & 3) * 8;
    int pf8 = ((quad + (l15 >> 1)) & 3) * 8;

    f32x4 acc[4][4];
    #pragma unroll
    for (int i = 0; i < 4; ++i)
        #pragma unroll
        for (int j = 0; j < 4; ++j) acc[i][j] = (f32x4){0.f, 0.f, 0.f, 0.f};

    for (int kt = 0; kt < K; kt += BK) {
        #pragma unroll
        for (int i = 0; i < 2; ++i) {
            int r = i * 64 + wv * 16 + rsub;
            gload16(Ah + (size_t)(bm + r) * K + kt + gc8, &Ash[r * BK + lc8]);
            gload16(Bh + (size_t)(bn + r) * K + kt + gc8, &Bsh[r * BK + lc8]);
        }
        __syncthreads();
        bf16x8 fah[4], fbh[4];
        #pragma unroll
        for (int i = 0; i < 4; ++i)
            fah[i] = *(const bf16x8*)&Ash[(wr * 64 + i * 16 + l15) * BK + pf8];
        #pragma unroll
        for (int j = 0; j < 4; ++j)
            fbh[j] = *(const bf16x8*)&Bsh[(wc * 64 + j * 16 + l15) * BK + pf8];
        #pragma unroll
        for (int i = 0; i < 4; ++i)
            #pragma unroll
            for (int j = 0; j < 4; ++j)
                acc[i][j] = MFMA16(fah[i], fbh[j], acc[i][j]);
        __syncthreads();
    }

    float alpha = alphap[0];
    float scale = powf(sqrtf((float)N3C) / logf(1.0f + (float)N3C), alpha);
    int segc0 = bn + wc * 64;          // wave-uniform
    int seg = segc0 >> 10;             // 0=Q 1=K 2=V
    int h = (segc0 >> 6) & 15;
    int bglob = bm >> 11;
    int bh = bglob * NH + h;

    if (seg < 2) {
        u16* dst = (seg == 0) ? Qb : Kb;
        float qs = (seg == 0) ? 0.125f : 1.0f;
        #pragma unroll
        for (int i = 0; i < 4; ++i) {
            int tb = bm + wr * 64 + i * 16 + quad * 4;
            #pragma unroll
            for (int r = 0; r < 4; ++r) {
                int row = tb + r;
                int t = row & (TSEQ - 1);
                float rs = rowsq[row];
                float y[4];
                #pragma unroll
                for (int j = 0; j < 4; ++j) {
                    int col = segc0 + j * 16 + l15;
                    float dot = acc[i][j][r];
                    float dist = rs + colsq[col] - 2.0f * dot + EPSY;
                    y[j] = dot * dot / dist * scale + bias[col];
                }
                float2 sc0 = ropeSC[t * 32 + l15];
                float2 sc1 = ropeSC[t * 32 + 16 + l15];
                float c0 = sc0.x, s0 = sc0.y, c1 = sc1.x, s1 = sc1.y;
                size_t ob = ((size_t)bh * TSEQ + t) * HD;
                dst[ob + l15]      = f2bf((y[0] * c0 - y[2] * s0) * qs);
                dst[ob + 16 + l15] = f2bf((y[1] * c1 - y[3] * s1) * qs);
                dst[ob + 32 + l15] = f2bf((y[2] * c0 + y[0] * s0) * qs);
                dst[ob + 48 + l15] = f2bf((y[3] * c1 + y[1] * s1) * qs);
            }
        }
    } else {
        #pragma unroll
        for (int i = 0; i < 4; ++i) {
            int tb = bm + wr * 64 + i * 16 + quad * 4;
            int t0 = tb & (TSEQ - 1);
            #pragma unroll
            for (int j = 0; j < 4; ++j) {
                int col = segc0 + j * 16 + l15;
                int d = j * 16 + l15;
                float cs = colsq[col], bi = bias[col];
                ushort4 pk;
                u16* pp = (u16*)&pk;
                #pragma unroll
                for (int r = 0; r < 4; ++r) {
                    float dot = acc[i][j][r];
                    float dist = rowsq[tb + r] + cs - 2.0f * dot + EPSY;
                    pp[r] = f2bf(dot * dot / dist * scale + bi);
                }
                *(ushort4*)(Vt + ((size_t)bh * HD + d) * TSEQ + t0) = pk;
            }
        }
    }
}

// ---------------------------------------------------------------------------
// GEMM2: single-bf16 MFMA + yat epilogue, fp32 out. 128x64 tile, swizzled.
__global__ __launch_bounds__(256, 4) void gemm_yat_mfma(
    const u16* __restrict__ Ah, const u16* __restrict__ Bh,
    const float* __restrict__ bias, const float* __restrict__ rowsq,
    const float* __restrict__ colsq, const float* __restrict__ alphap,
    float* __restrict__ outp, int M, int N, int K, float outf) {
    constexpr int BM = 128, BN = 64, BK = 32;
    __shared__ u16 Ash[BM * BK], Bsh[BN * BK];
    int tid = threadIdx.x;
    int lane = tid & 63, wv = tid >> 6;
    int quad = lane >> 4, l15 = lane & 15;
    int bm = blockIdx.y * BM, bn = blockIdx.x * BN;
    int rsub = lane >> 2;
    int lc8 = (lane & 3) * 8;
    int gc8 = (((lane & 3) - (rsub >> 1)) & 3) * 8;
    int pf8 = ((quad + (l15 >> 1)) & 3) * 8;

    f32x4 acc[2][4];
    #pragma unroll
    for (int i = 0; i < 2; ++i)
        #pragma unroll
        for (int j = 0; j < 4; ++j) acc[i][j] = (f32x4){0.f, 0.f, 0.f, 0.f};

    for (int kt = 0; kt < K; kt += BK) {
        #pragma unroll
        for (int i = 0; i < 2; ++i) {
            int r = i * 64 + wv * 16 + rsub;
            gload16(Ah + (size_t)(bm + r) * K + kt + gc8, &Ash[r * BK + lc8]);
        }
        {
            int r = wv * 16 + rsub;
            gload16(Bh + (size_t)(bn + r) * K + kt + gc8, &Bsh[r * BK + lc8]);
        }
        __syncthreads();
        bf16x8 fah[2], fbh[4];
        #pragma unroll
        for (int i = 0; i < 2; ++i)
            fah[i] = *(const bf16x8*)&Ash[(wv * 32 + i * 16 + l15) * BK + pf8];
        #pragma unroll
        for (int j = 0; j < 4; ++j)
            fbh[j] = *(const bf16x8*)&Bsh[(j * 16 + l15) * BK + pf8];
        #pragma unroll
        for (int i = 0; i < 2; ++i)
            #pragma unroll
            for (int j = 0; j < 4; ++j)
                acc[i][j] = MFMA16(fah[i], fbh[j], acc[i][j]);
        __syncthreads();
    }

    float alpha = alphap[0];
    float scale = powf(sqrtf(outf) / logf(1.0f + outf), alpha);
    #pragma unroll
    for (int j = 0; j < 4; ++j) {
        int col = bn + j * 16 + l15;
        float cs = colsq[col], bi = bias[col];
        #pragma unroll
        for (int i = 0; i < 2; ++i) {
            #pragma unroll
            for (int r = 0; r < 4; ++r) {
                int row = bm + wv * 32 + i * 16 + quad * 4 + r;
                float dot = acc[i][j][r];
                float dist = rowsq[row] + cs - 2.0f * dot + EPSY;
                outp[(size_t)row * N + col] = dot * dot / dist * scale + bi;
            }
        }
    }
}

// ---------------------------------------------------------------------------
// S^T bf16 MFMA causal flash attention, fixed-shift softmax.
// 128-thread blocks (2 waves, 32 queries): grid (bh=32, 64) where
// y -> qb = 31-(y>>1) (longest first), half = y&1. 8 blocks/CU co-resident
// (vs 4 at 256-thr) — doubles the grid-limited occupancy. blockIdx.x=bh
// keeps a bh's K/V on one XCD (R9: FETCH 122->12 MB). Epilogue: bf16 Chi
// + atomic osq.
__global__ __launch_bounds__(128) void attn_mfma(
    const u16* __restrict__ Qb, const u16* __restrict__ Kb,
    const u16* __restrict__ Vt, u16* __restrict__ Chi,
    float* __restrict__ osq) {
    __shared__ u16 Ksh[64 * 64];   // [key][d-chunks, rotated by key]
    __shared__ u16 Vsh[64 * 64];   // [d][key-chunks, rotated by d]
    int tid = threadIdx.x;
    int lane = tid & 63, wv = tid >> 6;       // wv in {0,1}
    int quad = lane >> 4, l15 = lane & 15;
    int bh = blockIdx.x;
    int b = bh >> 4, h = bh & 15;
    const u16* Qh = Qb + (size_t)bh * TSEQ * HD;
    const u16* Kh = Kb + (size_t)bh * TSEQ * HD;
    const u16* Vh = Vt + (size_t)bh * HD * TSEQ;
    const f32x4 zf = {0.f, 0.f, 0.f, 0.f};

    int qb = 31 - (blockIdx.y >> 1);
    int half = blockIdx.y & 1;
    int qw = qb * 64 + half * 32 + wv * 16;
    bf16x8 bq0 = *(const bf16x8*)(Qh + (size_t)(qw + l15) * HD + quad * 8);
    bf16x8 bq1 = *(const bf16x8*)(Qh + (size_t)(qw + l15) * HD + 32 + quad * 8);

    f32x4 o[4] = {zf, zf, zf, zf};
    float l = 0.f;

    for (int kt = 0; kt <= qb; ++kt) {
        int k0 = kt * 64;
        __syncthreads();
        #pragma unroll
        for (int p = 0; p < 4; ++p) {
            int lin = p * 128 + tid;          // [0,512)
            int rowi = lin >> 3, ch = lin & 7;
            int gk = (ch + rowi) & 7;
            gload16(Kh + (size_t)(k0 + rowi) * HD + gk * 8, &Ksh[lin * 8]);
            gload16(Vh + (size_t)rowi * TSEQ + k0 + gk * 8, &Vsh[lin * 8]);
        }
        __syncthreads();

        f32x4 st[4];
        #pragma unroll
        for (int mt = 0; mt < 4; ++mt) {
            int key = mt * 16 + l15;
            bf16x8 a0 = *(const bf16x8*)&Ksh[key * 64 + ((quad - key) & 7) * 8];
            bf16x8 a1 = *(const bf16x8*)&Ksh[key * 64 + ((4 + quad - key) & 7) * 8];
            st[mt] = MFMA16(a0, bq0, zf);
            st[mt] = MFMA16(a1, bq1, st[mt]);
        }
        if (kt == qb) {
            int q = qw + l15;
            #pragma unroll
            for (int mt = 0; mt < 4; ++mt)
                #pragma unroll
                for (int r = 0; r < 4; ++r)
                    if (k0 + mt * 16 + quad * 4 + r > q) st[mt][r] = -1e30f;
        }
        u32 pp[4][2];
        #pragma unroll
        for (int mt = 0; mt < 4; ++mt) {
            float p0 = __expf(st[mt][0]);
            float p1 = __expf(st[mt][1]);
            float p2 = __expf(st[mt][2]);
            float p3 = __expf(st[mt][3]);
            l += (p0 + p1) + (p2 + p3);
            pp[mt][0] = (u32)f2bf(p0) | ((u32)f2bf(p1) << 16);
            pp[mt][1] = (u32)f2bf(p2) | ((u32)f2bf(p3) << 16);
        }
        // PV: shuffle BOTH mt-candidates, select on the DESTINATION side.
        #pragma unroll
        for (int s = 0; s < 2; ++s) {
            u32 bw[4];
            #pragma unroll
            for (int w = 0; w < 4; ++w) {
                int srcl = (((quad & 1) * 2 + (w >> 1)) << 4) + l15;
                u32 vlo = (u32)__shfl((int)pp[2 * s][w & 1], srcl, 64);
                u32 vhi = (u32)__shfl((int)pp[2 * s + 1][w & 1], srcl, 64);
                bw[w] = (quad & 2) ? vhi : vlo;
            }
            bf16x8 bfr;
            *(u32*)&((short*)&bfr)[0] = bw[0];
            *(u32*)&((short*)&bfr)[2] = bw[1];
            *(u32*)&((short*)&bfr)[4] = bw[2];
            *(u32*)&((short*)&bfr)[6] = bw[3];
            #pragma unroll
            for (int dt = 0; dt < 4; ++dt) {
                int d = dt * 16 + l15;
                bf16x8 av = *(const bf16x8*)&Vsh[d * 64 + ((s * 4 + quad - d) & 7) * 8];
                o[dt] = MFMA16(av, bfr, o[dt]);
            }
        }
    }

    // deferred cross-quad l reduction, bf16 write, fused row-sumsq
    l += __shfl_xor(l, 16, 64);
    l += __shfl_xor(l, 32, 64);
    float inv = 1.0f / l;
    int row = (b << 11) + qw + l15;
    float ss = 0.f;
    #pragma unroll
    for (int dt = 0; dt < 4; ++dt) {
        float v0 = o[dt][0] * inv, v1 = o[dt][1] * inv;
        float v2 = o[dt][2] * inv, v3 = o[dt][3] * inv;
        ss += v0 * v0 + v1 * v1 + v2 * v2 + v3 * v3;
        ushort4 pk;
        pk.x = f2bf(v0); pk.y = f2bf(v1); pk.z = f2bf(v2); pk.w = f2bf(v3);
        *(ushort4*)(Chi + (size_t)row * CDIM + h * HD + dt * 16 + quad * 4) = pk;
    }
    ss += __shfl_xor(ss, 16, 64);
    ss += __shfl_xor(ss, 32, 64);
    if (quad == 0) atomicAdd(osq + row, ss);
}

// ---------------------------------------------------------------------------
extern "C" void kernel_launch(void* const* d_in, const int* in_sizes, int n_in,
                              void* d_out, int out_size, void* d_ws, size_t ws_size,
                              hipStream_t stream) {
    const float* x      = (const float*)d_in[0];
    const float* w_attn = (const float*)d_in[2];
    const float* b_attn = (const float*)d_in[3];
    const float* a_attn = (const float*)d_in[4];
    const float* w_proj = (const float*)d_in[5];
    const float* b_proj = (const float*)d_in[6];
    const float* a_proj = (const float*)d_in[7];
    float* outp = (float*)d_out;

    char* ws = (char*)d_ws;
    float* ksq = (float*)(ws);
    float* xsq = (float*)(ws + 16384);
    float* osq = (float*)(ws + 32768);
    char* pA  = ws + 65536;                    // 16.78 MB: Ahi -> Chi
    u16* Ahi = (u16*)pA;
    u16* Chi = (u16*)pA;                       // alias (Ahi dead after GEMM1)
    char* pWt = pA + 16777216;                 // 6.29 MB
    u16* Wthi = (u16*)pWt;
    char* pWp = pWt + 6291456;                 // 2.10 MB
    u16* Wphi = (u16*)pWp;
    char* pQ = pWp + 2097152;                  // 25.17 MB: Qb,Kb,Vt
    u16* Qb = (u16*)pQ;
    u16* Kb = (u16*)(pQ + 8388608);
    u16* Vt = (u16*)(pQ + 16777216);
    float2* ropeSC = (float2*)(pQ + 25165824); // 512 KB

    prep_kernel<<<5440, 256, 0, stream>>>(
        x, w_attn, w_proj, Ahi, Wthi, Wphi, ksq, xsq, osq, ropeSC);
    gemm1_fused<<<dim3(N3C / 128, (BATCH * TSEQ) / 128), 256, 0, stream>>>(
        Ahi, Wthi, b_attn, xsq, ksq, a_attn, ropeSC, Qb, Kb, Vt);
    attn_mfma<<<dim3(BATCH * NH, 64), 128, 0, stream>>>(Qb, Kb, Vt, Chi, osq);
    gemm_yat_mfma<<<dim3(CDIM / 64, (BATCH * TSEQ) / 128), 256, 0, stream>>>(
        Chi, Wphi, b_proj, osq, ksq + N3C, a_proj, outp,
        BATCH * TSEQ, CDIM, CDIM, (float)CDIM);
}